// Round 9
// baseline (1048.254 us; speedup 1.0000x reference)
//
#include <hip/hip_runtime.h>

#define TPB 256
#define CTPB 512

__device__ __forceinline__ void fma4(float4& a, float s, const float4 b){
  a.x = fmaf(s,b.x,a.x); a.y = fmaf(s,b.y,a.y);
  a.z = fmaf(s,b.z,a.z); a.w = fmaf(s,b.w,a.w);
}

__device__ __forceinline__ float elem(const float4& f, int r){
  return r==0?f.x:(r==1?f.y:(r==2?f.z:f.w));
}

__device__ __forceinline__ int vox(int b,int z,int y,int x,int ld){
  return ((((((b<<ld)|z)<<ld)|y)<<ld)|x);
}

__device__ __forceinline__ float chan(const float4&a0,const float4&a1,const float4&a2,const float4&a3,int c){
  const float4& f = (c<4)?a0:((c<8)?a1:((c<12)?a2:a3));
  int r=c&3;
  return r==0?f.x:(r==1?f.y:(r==2?f.z:f.w));
}

// block-hierarchical list append: ballot -> LDS -> ONE global atomic per block.
__device__ __forceinline__ void append_list(bool a, int v, int* __restrict__ list, int* __restrict__ cnt){
  __shared__ int lcnt, lbase;
  __shared__ int woff[TPB/64];
  if(threadIdx.x==0) lcnt=0;
  __syncthreads();
  unsigned long long bl = __ballot(a);
  int lane = threadIdx.x & 63;
  int wv = threadIdx.x >> 6;
  if(lane==0){ int pop=__popcll(bl); woff[wv] = pop ? atomicAdd(&lcnt,pop) : 0; }
  __syncthreads();
  if(threadIdx.x==0 && lcnt) lbase = atomicAdd(cnt, lcnt);
  __syncthreads();
  if(a) list[lbase + woff[wv] + __popcll(bl & ((1ull<<lane)-1ull))] = v;
}

// stats for thread-per-voxel kernels (16 channels per thread)
__device__ __forceinline__ void stats_reduce(const float4&a0,const float4&a1,const float4&a2,const float4&a3,
                                             float* red, float* __restrict__ gsums){
  int lane=threadIdx.x&63, wv=threadIdx.x>>6, nw=blockDim.x>>6;
  #pragma unroll
  for(int c=0;c<16;c++){
    float x = chan(a0,a1,a2,a3,c);
    float q = x*x;
    for(int o=32;o>0;o>>=1){ x+=__shfl_down(x,o,64); q+=__shfl_down(q,o,64); }
    if(lane==0){ red[wv*32+c]=x; red[wv*32+16+c]=q; }
  }
  __syncthreads();
  if(threadIdx.x<32){
    float t=0.f;
    for(int w=0;w<nw;w++) t+=red[w*32+threadIdx.x];
    atomicAdd(&gsums[threadIdx.x], t);
  }
}

// stats for co-split kernels: thread holds channels 4*sub..4*sub+3 (sub = tid&3)
__device__ __forceinline__ void stats_reduce4(const float4&a, float* red, float* __restrict__ gsums){
  int lane=threadIdx.x&63, wv=threadIdx.x>>6, nw=blockDim.x>>6;
  float sx[4]={a.x,a.y,a.z,a.w};
  float sq[4]={a.x*a.x,a.y*a.y,a.z*a.z,a.w*a.w};
  for(int o=32;o>=4;o>>=1){
    #pragma unroll
    for(int k=0;k<4;k++){ sx[k]+=__shfl_down(sx[k],o,64); sq[k]+=__shfl_down(sq[k],o,64); }
  }
  if(lane<4){
    #pragma unroll
    for(int k=0;k<4;k++){ red[wv*32+lane*4+k]=sx[k]; red[wv*32+16+lane*4+k]=sq[k]; }
  }
  __syncthreads();
  if(threadIdx.x<32){
    float t=0.f;
    for(int w=0;w<nw;w++) t+=red[w*32+threadIdx.x];
    atomicAdd(&gsums[threadIdx.x], t);
  }
}

// paired variant: two voxels' accs per thread
__device__ __forceinline__ void stats_reduce4p(const float4&a, const float4&b, float* red, float* __restrict__ gsums){
  int lane=threadIdx.x&63, wv=threadIdx.x>>6, nw=blockDim.x>>6;
  float sx[4]={a.x+b.x,a.y+b.y,a.z+b.z,a.w+b.w};
  float sq[4]={a.x*a.x+b.x*b.x,a.y*a.y+b.y*b.y,a.z*a.z+b.z*b.z,a.w*a.w+b.w*b.w};
  for(int o=32;o>=4;o>>=1){
    #pragma unroll
    for(int k=0;k<4;k++){ sx[k]+=__shfl_down(sx[k],o,64); sq[k]+=__shfl_down(sq[k],o,64); }
  }
  if(lane<4){
    #pragma unroll
    for(int k=0;k<4;k++){ red[wv*32+lane*4+k]=sx[k]; red[wv*32+16+lane*4+k]=sq[k]; }
  }
  __syncthreads();
  if(threadIdx.x<32){
    float t=0.f;
    for(int w=0;w<nw;w++) t+=red[w*32+threadIdx.x];
    atomicAdd(&gsums[threadIdx.x], t);
  }
}

__global__ __launch_bounds__(TPB) void k_scatter(const float* __restrict__ data, const int* __restrict__ cl,
                                                 int n, float* __restrict__ c0){
  int i = blockIdx.x*blockDim.x + threadIdx.x;
  if(i>=n) return;
  int z=(int)data[i*5+0], y=(int)data[i*5+1], x=(int)data[i*5+2];
  atomicAdd(&c0[vox(cl[i],z,y,x,6)], 1.0f);
}

// ---- ordered 3-phase compaction of the L0 occupancy grid ----
__global__ __launch_bounds__(TPB) void k_cnt0(const float* __restrict__ c0, int n, int* __restrict__ bc){
  int i = blockIdx.x*TPB + threadIdx.x;
  bool a = (i<n) && (c0[i]>0.f);
  unsigned long long bl = __ballot(a);
  __shared__ int wcnt[TPB/64];
  int lane=threadIdx.x&63, wv=threadIdx.x>>6;
  if(lane==0) wcnt[wv]=__popcll(bl);
  __syncthreads();
  if(threadIdx.x==0) bc[blockIdx.x]=wcnt[0]+wcnt[1]+wcnt[2]+wcnt[3];
}

__global__ __launch_bounds__(1024) void k_scan0(int* __restrict__ bc, int nb, int* __restrict__ total){
  __shared__ int s[1024];
  int t=threadIdx.x, b4=t*4;
  int v0 = (b4+0<nb)?bc[b4+0]:0;
  int v1 = (b4+1<nb)?bc[b4+1]:0;
  int v2 = (b4+2<nb)?bc[b4+2]:0;
  int v3 = (b4+3<nb)?bc[b4+3]:0;
  int sum=v0+v1+v2+v3;
  s[t]=sum; __syncthreads();
  for(int o=1;o<1024;o<<=1){
    int x = (t>=o)? s[t-o] : 0;
    __syncthreads();
    s[t]+=x;
    __syncthreads();
  }
  int excl=s[t]-sum;
  if(b4+0<nb) bc[b4+0]=excl;
  if(b4+1<nb) bc[b4+1]=excl+v0;
  if(b4+2<nb) bc[b4+2]=excl+v0+v1;
  if(b4+3<nb) bc[b4+3]=excl+v0+v1+v2;
  if(t==1023) *total = s[1023];
}

__global__ __launch_bounds__(TPB) void k_emit0(const float* __restrict__ c0, int n,
                                               const int* __restrict__ bc, int* __restrict__ list){
  int i = blockIdx.x*TPB + threadIdx.x;
  bool a = (i<n) && (c0[i]>0.f);
  unsigned long long bl = __ballot(a);
  __shared__ int woff[TPB/64];
  __shared__ int wpre[TPB/64];
  int lane=threadIdx.x&63, wv=threadIdx.x>>6;
  if(lane==0) woff[wv]=__popcll(bl);
  __syncthreads();
  if(threadIdx.x==0){ int acc=0; for(int w=0;w<TPB/64;w++){ wpre[w]=acc; acc+=woff[w]; } }
  __syncthreads();
  if(a) list[bc[blockIdx.x] + wpre[wv] + __popcll(bl&((1ull<<lane)-1ull))] = i;
}

__global__ __launch_bounds__(TPB) void k_markparent_compact(const int* __restrict__ listF, const int* __restrict__ cntF,
        int ldf, int* __restrict__ g, int* __restrict__ listC, int* __restrict__ cntC){
  int i = blockIdx.x*TPB + threadIdx.x;
  bool first=false; int p=0;
  if(i < *cntF){
    int v=listF[i];
    int dm=(1<<ldf)-1;
    int x=v&dm, y=(v>>ldf)&dm, z=(v>>(2*ldf))&dm, b=v>>(3*ldf);
    p=vox(b,z>>1,y>>1,x>>1,ldf-1);
    first = (atomicExch(&g[p],1)==0);
  }
  append_list(first,p,listC,cntC);
}

__global__ __launch_bounds__(TPB) void k_sparsify_compact(float* __restrict__ X, float* __restrict__ Y,
        const int* __restrict__ listA, const int* __restrict__ cntA,
        int* __restrict__ listB, int* __restrict__ cntB, int* __restrict__ gmask){
  int i = blockIdx.x*TPB + threadIdx.x;
  bool keep=false; int v=0;
  if(i < *cntA){
    v = listA[i];
    keep = X[(size_t)v<<4] > 0.f;
    if(!keep){
      float4 zz = make_float4(0,0,0,0);
      float4* px=(float4*)(X+((size_t)v<<4)); px[0]=zz;px[1]=zz;px[2]=zz;px[3]=zz;
      float4* py=(float4*)(Y+((size_t)v<<4)); py[0]=zz;py[1]=zz;py[2]=zz;py[3]=zz;
      if(gmask) gmask[v]=0;
    }
  }
  append_list(keep,v,listB,cntB);
}

// prepare: 1 -> 16 ch, k=3 SAME; LDS weights; fused stats
__global__ __launch_bounds__(TPB) void k_prep_l(const float* __restrict__ c0, const int* __restrict__ list,
          const int* __restrict__ cnt, const float* __restrict__ w, float* __restrict__ X,
          float* __restrict__ gsums){
  __shared__ float wl[432];
  __shared__ float red[(TPB/64)*32];
  for(int i=threadIdx.x;i<432;i+=TPB) wl[i]=w[i];
  __syncthreads();
  int i = blockIdx.x*TPB + threadIdx.x;
  bool act = i < *cnt;
  float4 a0=make_float4(0,0,0,0), a1=a0, a2=a0, a3=a0;
  if(act){
    int v=list[i];
    int x=v&63, y=(v>>6)&63, z=(v>>12)&63, b=v>>18;
    for(int dz=0;dz<3;dz++){ int zz=z+dz-1; if((unsigned)zz>=64u) continue;
      for(int dy=0;dy<3;dy++){ int yy=y+dy-1; if((unsigned)yy>=64u) continue;
        for(int dx=0;dx<3;dx++){ int xx=x+dx-1; if((unsigned)xx>=64u) continue;
          float av = c0[vox(b,zz,yy,xx,6)];
          if(av==0.f) continue;
          const float4* wv=(const float4*)&wl[((dz*3+dy)*3+dx)<<4];
          fma4(a0,av,wv[0]); fma4(a1,av,wv[1]); fma4(a2,av,wv[2]); fma4(a3,av,wv[3]);
        }
      }
    }
    float4* o=(float4*)(X+((size_t)v<<4));
    o[0]=a0;o[1]=a1;o[2]=a2;o[3]=a3;
  }
  stats_reduce(a0,a1,a2,a3,red,gsums);
}

// 16->16 k=3 SAME conv, co-split + voxel-paired, ci-chunked (low VGPR)
__global__ __launch_bounds__(CTPB) void k_conv3_l(const float* __restrict__ Xin, const int* __restrict__ list,
      const int* __restrict__ cnt, const float* __restrict__ w, float* __restrict__ Xout, int ld){
  __shared__ float wl[6912];
  int nwork = *cnt;
  int npairs = (nwork+1)>>1;
  if((int)((blockIdx.x*CTPB)>>2) >= npairs) return;
  for(int i=threadIdx.x;i<6912;i+=CTPB) wl[i]=w[i];
  __syncthreads();
  int t = blockIdx.x*CTPB + threadIdx.x;
  int p = t>>2, sub = t&3;
  if(p >= npairs) return;
  int v0 = list[2*p];
  bool has1 = (2*p+1) < nwork;
  int v1 = has1 ? list[2*p+1] : v0;
  int d=1<<ld, dm=d-1;
  int x0=v0&dm, y0=(v0>>ld)&dm, z0=(v0>>(2*ld))&dm, bb0=v0>>(3*ld);
  int x1=v1&dm, y1=(v1>>ld)&dm, z1=(v1>>(2*ld))&dm, bb1=v1>>(3*ld);
  float4 acc0=make_float4(0,0,0,0), acc1=acc0;
  for(int dz=0;dz<3;dz++){
    int zz0=z0+dz-1, zz1=z1+dz-1;
    bool vz0=(unsigned)zz0<(unsigned)d, vz1=(unsigned)zz1<(unsigned)d;
    if(!(vz0||vz1)) continue;
    for(int dy=0;dy<3;dy++){
      int yy0=y0+dy-1, yy1=y1+dy-1;
      bool vy0=vz0&&((unsigned)yy0<(unsigned)d), vy1=vz1&&((unsigned)yy1<(unsigned)d);
      if(!(vy0||vy1)) continue;
      const float* r0 = Xin + ((size_t)vox(bb0,vy0?zz0:0,vy0?yy0:0,0,ld)<<4);
      const float* r1 = Xin + ((size_t)vox(bb1,vy1?zz1:0,vy1?yy1:0,0,ld)<<4);
      const float* wrow = &wl[(((dz*3+dy)*3)<<8) + (sub<<2)];
      for(int dx=0;dx<3;dx++){
        int xx0=x0+dx-1, xx1=x1+dx-1;
        bool va0=vy0&&((unsigned)xx0<(unsigned)d), va1=vy1&&((unsigned)xx1<(unsigned)d);
        if(!(va0||va1)) continue;
        const float4* p0=(const float4*)(r0+((size_t)xx0<<4));
        const float4* p1=(const float4*)(r1+((size_t)xx1<<4));
        const float* wt = wrow + (dx<<8);
        float4 zz4=make_float4(0,0,0,0);
        #pragma unroll
        for(int cb=0;cb<4;cb++){
          float4 s0 = va0 ? p0[cb] : zz4;
          float4 s1 = va1 ? p1[cb] : zz4;
          #pragma unroll
          for(int cq=0;cq<4;cq++){
            float4 wv = *(const float4*)(wt + (((cb<<2)|cq)<<4));
            fma4(acc0, elem(s0,cq), wv);
            fma4(acc1, elem(s1,cq), wv);
          }
        }
      }
    }
  }
  ((float4*)(Xout + ((size_t)v0<<4)))[sub] = acc0;
  if(has1) ((float4*)(Xout + ((size_t)v1<<4)))[sub] = acc1;
}

// k=4 pad(1,2) conv, co-split + voxel-paired, ci-chunked, two-phase weight staging; fused stats
__global__ __launch_bounds__(CTPB) void k_conv4_l(const float* __restrict__ Xin, const int* __restrict__ list,
      const int* __restrict__ cnt, const float* __restrict__ w, float* __restrict__ Xout, int ld,
      float* __restrict__ gsums){
  __shared__ float wl[8192];
  __shared__ float red[(CTPB/64)*32];
  int nwork = *cnt;
  int npairs = (nwork+1)>>1;
  if((int)((blockIdx.x*CTPB)>>2) >= npairs) return;
  int t = blockIdx.x*CTPB + threadIdx.x;
  int p = t>>2, sub = t&3;
  bool act = p < npairs;
  int v0=0,v1=0; bool has1=false;
  int x0=0,y0=0,z0=0,bb0=0,x1=0,y1=0,z1=0,bb1=0;
  int d=1<<ld, dm=d-1;
  if(act){
    v0 = list[2*p];
    has1 = (2*p+1) < nwork;
    v1 = has1 ? list[2*p+1] : v0;
    x0=v0&dm; y0=(v0>>ld)&dm; z0=(v0>>(2*ld))&dm; bb0=v0>>(3*ld);
    x1=v1&dm; y1=(v1>>ld)&dm; z1=(v1>>(2*ld))&dm; bb1=v1>>(3*ld);
  }
  float4 acc0=make_float4(0,0,0,0), acc1=acc0;
  for(int half=0;half<2;half++){
    __syncthreads();
    for(int k=threadIdx.x;k<8192;k+=CTPB) wl[k]=w[half*8192+k];
    __syncthreads();
    if(act){
      for(int dzl=0;dzl<2;dzl++){
        int dz=half*2+dzl;
        int zz0=z0+dz-1, zz1=z1+dz-1;
        bool vz0=(unsigned)zz0<(unsigned)d, vz1=(unsigned)zz1<(unsigned)d;
        if(!(vz0||vz1)) continue;
        for(int dy=0;dy<4;dy++){
          int yy0=y0+dy-1, yy1=y1+dy-1;
          bool vy0=vz0&&((unsigned)yy0<(unsigned)d), vy1=vz1&&((unsigned)yy1<(unsigned)d);
          if(!(vy0||vy1)) continue;
          const float* r0 = Xin + ((size_t)vox(bb0,vy0?zz0:0,vy0?yy0:0,0,ld)<<4);
          const float* r1 = Xin + ((size_t)vox(bb1,vy1?zz1:0,vy1?yy1:0,0,ld)<<4);
          const float* wrow = &wl[((dzl*4+dy)<<10) + (sub<<2)];
          for(int dx=0;dx<4;dx++){
            int xx0=x0+dx-1, xx1=x1+dx-1;
            bool va0=vy0&&((unsigned)xx0<(unsigned)d), va1=vy1&&((unsigned)xx1<(unsigned)d);
            if(!(va0||va1)) continue;
            const float4* p0=(const float4*)(r0+((size_t)xx0<<4));
            const float4* p1=(const float4*)(r1+((size_t)xx1<<4));
            const float* wt = wrow + (dx<<8);
            float4 zz4=make_float4(0,0,0,0);
            #pragma unroll
            for(int cb=0;cb<4;cb++){
              float4 s0 = va0 ? p0[cb] : zz4;
              float4 s1 = va1 ? p1[cb] : zz4;
              #pragma unroll
              for(int cq=0;cq<4;cq++){
                float4 wv = *(const float4*)(wt + (((cb<<2)|cq)<<4));
                fma4(acc0, elem(s0,cq), wv);
                fma4(acc1, elem(s1,cq), wv);
              }
            }
          }
        }
      }
    }
  }
  if(act){
    ((float4*)(Xout + ((size_t)v0<<4)))[sub] = acc0;
    if(has1) ((float4*)(Xout + ((size_t)v1<<4)))[sub] = acc1;
    if(!has1) acc1 = make_float4(0,0,0,0);   // don't double-count odd tail in BN stats
  }
  __syncthreads();
  stats_reduce4p(acc0, acc1, red, gsums);
}

// strided k=2 s=2 VALID down-conv, co-split; fused stats
__global__ __launch_bounds__(TPB) void k_down_l(const float* __restrict__ Xin, const int* __restrict__ list,
      const int* __restrict__ cnt, const float* __restrict__ w, float* __restrict__ Xout, int ldc,
      float* __restrict__ gsums){
  __shared__ float wl[2048];
  __shared__ float red[(TPB/64)*32];
  int nwork = *cnt;
  for(int k=threadIdx.x;k<2048;k+=TPB) wl[k]=w[k];
  __syncthreads();
  int t = blockIdx.x*TPB + threadIdx.x;
  int i = t>>2, sub = t&3;
  bool act = i < nwork;
  float4 acc=make_float4(0,0,0,0);
  if(act){
    int v = list[i];
    int dm=(1<<ldc)-1, ldf=ldc+1;
    int x=v&dm, y=(v>>ldc)&dm, z=(v>>(2*ldc))&dm, b=v>>(3*ldc);
    for(int dz=0;dz<2;dz++) for(int dy=0;dy<2;dy++) for(int dx=0;dx<2;dx++){
      const float4* sp=(const float4*)(Xin + ((size_t)vox(b,2*z+dz,2*y+dy,2*x+dx,ldf)<<4));
      float s[16];
      *(float4*)&s[0]=sp[0]; *(float4*)&s[4]=sp[1]; *(float4*)&s[8]=sp[2]; *(float4*)&s[12]=sp[3];
      const float* wt=&wl[((((dz<<1)|dy)<<1 | dx)<<8) + (sub<<2)];
      #pragma unroll
      for(int ci=0;ci<16;ci++)
        fma4(acc, s[ci], *(const float4*)(wt+(ci<<4)));
    }
    ((float4*)(Xout+((size_t)v<<4)))[sub] = acc;
  }
  stats_reduce4(acc, red, gsums);
}

// conv_transpose k=2 s=2 with BN+ReLU folded onto the coarse operand; LDS weights
__global__ __launch_bounds__(TPB) void k_upbn_l(const float* __restrict__ Xc, const int* __restrict__ list,
      const int* __restrict__ cnt, const float* __restrict__ w,
      const float* __restrict__ sums, const int* __restrict__ bncnt,
      const float* __restrict__ g, const float* __restrict__ bta,
      const int* __restrict__ gmask, float* __restrict__ Xf, int ldf){
  __shared__ float wl[2048];
  __shared__ float sc[16], sh[16];
  for(int k=threadIdx.x;k<2048;k+=TPB) wl[k]=w[k];
  if(threadIdx.x<16){
    int c=threadIdx.x;
    float n=(float)(*bncnt); if(n<1.f) n=1.f;
    float mean=sums[c]/n;
    float var=sums[16+c]/n - mean*mean;
    float s=g[c]/sqrtf(var+1e-4f);
    sc[c]=s; sh[c]=fmaf(-mean,s,bta[c]);
  }
  __syncthreads();
  int i = blockIdx.x*TPB + threadIdx.x;
  if(i >= *cnt) return;
  int v = list[i];
  int dm=(1<<ldf)-1, ldc=ldf-1;
  int x=v&dm, y=(v>>ldf)&dm, z=(v>>(2*ldf))&dm, b=v>>(3*ldf);
  int p = vox(b,z>>1,y>>1,x>>1,ldc);
  float4 a0=make_float4(0,0,0,0), a1=a0, a2=a0, a3=a0;
  if(gmask[p]!=0){
    const float4* sp=(const float4*)(Xc + ((size_t)p<<4));
    float s[16];
    *(float4*)&s[0]=sp[0]; *(float4*)&s[4]=sp[1]; *(float4*)&s[8]=sp[2]; *(float4*)&s[12]=sp[3];
    #pragma unroll
    for(int ci=0;ci<16;ci++){ float xh=fmaf(s[ci],sc[ci],sh[ci]); s[ci]=xh>0.f?xh:0.f; }
    int tpar = ((((z&1)^1)<<1 | ((y&1)^1))<<1) | ((x&1)^1);
    const float* wt=&wl[tpar<<8];
    #pragma unroll
    for(int ci=0;ci<16;ci++){
      float av=s[ci];
      const float4* wv=(const float4*)(wt+(ci<<4));
      fma4(a0,av,wv[0]); fma4(a1,av,wv[1]); fma4(a2,av,wv[2]); fma4(a3,av,wv[3]);
    }
  }
  float4* o=(float4*)(Xf+((size_t)v<<4));
  o[0]=a0;o[1]=a1;o[2]=a2;o[3]=a3;
}

__global__ __launch_bounds__(TPB) void k_bnapply(float* __restrict__ X, const int* __restrict__ list,
        const int* __restrict__ cnt, const float* __restrict__ sums,
        const float* __restrict__ g, const float* __restrict__ bta){
  __shared__ float sc[16], sh[16];
  if(threadIdx.x<16){
    int c=threadIdx.x;
    float n=(float)(*cnt); if(n<1.f) n=1.f;
    float mean=sums[c]/n;
    float var=sums[16+c]/n - mean*mean;
    float s=g[c]/sqrtf(var+1e-4f);
    sc[c]=s; sh[c]=fmaf(-mean,s,bta[c]);
  }
  __syncthreads();
  int i = blockIdx.x*TPB + threadIdx.x;
  if(i>=*cnt) return;
  float* p = X + ((size_t)list[i]<<4);
  #pragma unroll
  for(int c=0;c<16;c++){
    float xh = fmaf(p[c], sc[c], sh[c]);
    p[c] = xh>0.f ? xh : 0.f;
  }
}

__global__ __launch_bounds__(TPB) void k_hidden(const float* __restrict__ X3, float* __restrict__ out){
  int i = blockIdx.x*TPB + threadIdx.x;
  if(i>=4*8192) return;
  int b=i>>13, r=i&8191, c=r>>9, s=r&511;
  out[i] = X3[(((size_t)((b<<9)|s))<<4)|c];
}

// output conv 16 -> 1, k=3 SAME; LDS weights
__global__ __launch_bounds__(TPB) void k_final_l(const float* __restrict__ Xin, const int* __restrict__ list,
      const int* __restrict__ cnt, const float* __restrict__ w, float* __restrict__ out){
  __shared__ float wl[432];
  for(int k=threadIdx.x;k<432;k+=TPB) wl[k]=w[k];
  __syncthreads();
  int i = blockIdx.x*TPB + threadIdx.x;
  if(i >= *cnt) return;
  int v = list[i];
  float acc=0.f;
  int x=v&63, y=(v>>6)&63, z=(v>>12)&63, b=v>>18;
  for(int dz=0;dz<3;dz++){ int zz=z+dz-1; if((unsigned)zz>=64u) continue;
    for(int dy=0;dy<3;dy++){ int yy=y+dy-1; if((unsigned)yy>=64u) continue;
      for(int dx=0;dx<3;dx++){ int xx=x+dx-1; if((unsigned)xx>=64u) continue;
        const float* sp = Xin + ((size_t)vox(b,zz,yy,xx,6)<<4);
        const float* wt = &wl[((dz*3+dy)*3+dx)<<4];
        #pragma unroll
        for(int ci=0;ci<16;ci++) acc = fmaf(sp[ci], wt[ci], acc);
      }
    }
  }
  out[v]=acc;
}

static inline int nb(int n){ return (n+TPB-1)/TPB; }
static inline int nbP(int n){ return ((4*((n+1)>>1))+CTPB-1)/CTPB; }  // paired co-split grids
static inline size_t rbytes(int ld){ return ((size_t)4<<(3*ld))*64; }

extern "C" void kernel_launch(void* const* d_in, const int* in_sizes, int n_in,
                              void* d_out, int out_size, void* d_ws, size_t ws_size,
                              hipStream_t stream){
  const float* data   = (const float*)d_in[0];
  const int*   cl     = (const int*)d_in[1];
  const float* w_prep = (const float*)d_in[2];
  const float* enc_g  = (const float*)d_in[3];
  const float* enc_b  = (const float*)d_in[4];
  const float* enc_ws = (const float*)d_in[5];
  const float* enc_wd = (const float*)d_in[6];
  const float* dec_g  = (const float*)d_in[7];
  const float* dec_b  = (const float*)d_in[8];
  const float* dec_wu = (const float*)d_in[9];
  const float* dec_w3 = (const float*)d_in[10];
  const float* dec_w4 = (const float*)d_in[11];
  const float* w_out  = (const float*)d_in[12];
  int N = in_sizes[0]/5;
  float* outp = (float*)d_out;

  const size_t FEAT_ROOMY = 38305792;
  const size_t FEAT_TIGHT = 33554432;
  const size_t TAILN      = 1048576 + 149504 + 224 + 16 + 4096 + 821248;
  bool roomy = ws_size >= (FEAT_ROOMY + TAILN)*sizeof(float);

  float* ws = (float*)d_ws;
  float *A[4]={0,0,0,0}, *B[4]={0,0,0,0}, *X=0, *Y=0;
  size_t featsz;
  if(roomy){
    A[0]=ws;            B[0]=A[0]+16777216;
    A[1]=B[0]+16777216; B[1]=A[1]+2097152;
    A[2]=B[1]+2097152;  B[2]=A[2]+262144;
    A[3]=B[2]+262144;
    featsz=FEAT_ROOMY;
  } else { X=ws; Y=X+16777216; featsz=FEAT_TIGHT; }
  float* c0 = ws + featsz;
  int* g1=(int*)(c0+1048576); int* g2=g1+131072; int* g3=g2+16384;
  float* sums=(float*)(g3+2048);
  int* counts=(int*)(sums+224);
  int* bc=counts+16;
  int* l0a=bc+4096; int* l0b=l0a+262144; int* l1a=l0b+262144; int* l1b=l1a+131072;
  int* l2a=l1b+131072; int* l2b=l2a+16384; int* l3=l2b+16384;
  int* la[4]={l0a,l1a,l2a,l3};
  int* lb[3]={l0b,l1b,l2b};
  int* g[4]={nullptr,g1,g2,g3};
  int b0 = N<262144?N:262144;
  int bounds[4]={b0,131072,16384,2048};

  hipMemsetAsync(ws, 0, featsz*sizeof(float), stream);
  hipMemsetAsync(c0, 0, (1048576+149504+224+16+4096)*sizeof(float), stream);

  k_scatter<<<nb(N),TPB,0,stream>>>(data, cl, N, c0);
  k_cnt0 <<<4096,TPB,0,stream>>>(c0, 1048576, bc);
  k_scan0<<<1,1024,0,stream>>>(bc, 4096, counts+0);
  k_emit0<<<4096,TPB,0,stream>>>(c0, 1048576, bc, l0a);

  if(roomy){
    k_prep_l<<<nb(b0),TPB,0,stream>>>(c0, l0a, counts+0, w_prep, A[0], sums);
    for(int i=0;i<3;i++){
      int ld=6-i;
      k_bnapply<<<nb(bounds[i]),TPB,0,stream>>>(A[i], la[i], counts+i, sums+32*i, enc_g+16*i, enc_b+16*i);
      k_conv3_l<<<nbP(bounds[i]),CTPB,0,stream>>>(A[i], la[i], counts+i, enc_ws+6912*i, B[i], ld);
      k_markparent_compact<<<nb(bounds[i]),TPB,0,stream>>>(la[i], counts+i, ld, g[i+1], la[i+1], counts+(i+1));
      k_down_l<<<nb(4*bounds[i+1]),TPB,0,stream>>>(B[i], la[i+1], counts+(i+1), enc_wd+2048*i, A[i+1], ld-1, sums+32*(i+1));
    }
    k_hidden<<<nb(32768),TPB,0,stream>>>(A[3], outp);
    for(int j=0;j<3;j++){
      int lvl=2-j, ldf=6-lvl;
      const int* bncnt = (j==0)? counts+3 : counts+4+(lvl+1);
      k_upbn_l<<<nb(bounds[lvl]),TPB,0,stream>>>(A[lvl+1], la[lvl], counts+lvl, dec_wu+2048*j,
            sums+32*(3+j), bncnt, dec_g+16*j, dec_b+16*j, g[lvl+1], A[lvl], ldf);
      k_conv3_l<<<nbP(bounds[lvl]),CTPB,0,stream>>>(A[lvl], la[lvl], counts+lvl, dec_w3+6912*j, B[lvl], ldf);
      k_sparsify_compact<<<nb(bounds[lvl]),TPB,0,stream>>>(B[lvl], A[lvl], la[lvl], counts+lvl, lb[lvl], counts+4+lvl, g[lvl]);
      float* ss = (j<2)? sums+32*(4+j) : sums+32*6;
      k_conv4_l<<<nbP(bounds[lvl]),CTPB,0,stream>>>(B[lvl], lb[lvl], counts+4+lvl, dec_w4+16384*j, A[lvl], ldf, ss);
    }
    hipMemsetAsync(outp+32768, 0, (size_t)1048576*sizeof(float), stream);
    k_final_l<<<nb(b0),TPB,0,stream>>>(A[0], lb[0], counts+4, w_out, outp+32768);
  } else {
    k_prep_l<<<nb(b0),TPB,0,stream>>>(c0, l0a, counts+0, w_prep, X, sums);
    float* cur=X; float* oth=Y; int ld=6;
    for(int i=0;i<3;i++){
      k_bnapply<<<nb(bounds[i]),TPB,0,stream>>>(cur, la[i], counts+i, sums+32*i, enc_g+16*i, enc_b+16*i);
      hipMemsetAsync(oth, 0, rbytes(ld), stream);
      k_conv3_l<<<nbP(bounds[i]),CTPB,0,stream>>>(cur, la[i], counts+i, enc_ws+6912*i, oth, ld);
      { float* t=cur; cur=oth; oth=t; }
      k_markparent_compact<<<nb(bounds[i]),TPB,0,stream>>>(la[i], counts+i, ld, g[i+1], la[i+1], counts+(i+1));
      hipMemsetAsync(oth, 0, rbytes(ld-1), stream);
      k_down_l<<<nb(4*bounds[i+1]),TPB,0,stream>>>(cur, la[i+1], counts+(i+1), enc_wd+2048*i, oth, ld-1, sums+32*(i+1));
      { float* t=cur; cur=oth; oth=t; }
      ld--;
    }
    k_hidden<<<nb(32768),TPB,0,stream>>>(cur, outp);
    for(int j=0;j<3;j++){
      int lvl=2-j, ldf=ld+1;
      const int* bncnt = (j==0)? counts+3 : counts+4+(lvl+1);
      hipMemsetAsync(oth, 0, rbytes(ldf), stream);
      k_upbn_l<<<nb(bounds[lvl]),TPB,0,stream>>>(cur, la[lvl], counts+lvl, dec_wu+2048*j,
            sums+32*(3+j), bncnt, dec_g+16*j, dec_b+16*j, g[lvl+1], oth, ldf);
      { float* t=cur; cur=oth; oth=t; }
      hipMemsetAsync(oth, 0, rbytes(ldf), stream);
      k_conv3_l<<<nbP(bounds[lvl]),CTPB,0,stream>>>(cur, la[lvl], counts+lvl, dec_w3+6912*j, oth, ldf);
      { float* t=cur; cur=oth; oth=t; }
      k_sparsify_compact<<<nb(bounds[lvl]),TPB,0,stream>>>(cur, oth, la[lvl], counts+lvl, lb[lvl], counts+4+lvl, g[lvl]);
      float* ss = (j<2)? sums+32*(4+j) : sums+32*6;
      k_conv4_l<<<nbP(bounds[lvl]),CTPB,0,stream>>>(cur, lb[lvl], counts+4+lvl, dec_w4+16384*j, oth, ldf, ss);
      { float* t=cur; cur=oth; oth=t; }
      ld=ldf;
    }
    hipMemsetAsync(outp+32768, 0, (size_t)1048576*sizeof(float), stream);
    k_final_l<<<nb(b0),TPB,0,stream>>>(cur, lb[0], counts+4, w_out, outp+32768);
  }
}

// Round 10
// 726.498 us; speedup vs baseline: 1.4429x; 1.4429x over previous
//
#include <hip/hip_runtime.h>

#define TPB 256
#define CTPB 512

__device__ __forceinline__ void fma4(float4& a, float s, const float4 b){
  a.x = fmaf(s,b.x,a.x); a.y = fmaf(s,b.y,a.y);
  a.z = fmaf(s,b.z,a.z); a.w = fmaf(s,b.w,a.w);
}

__device__ __forceinline__ int vox(int b,int z,int y,int x,int ld){
  return ((((((b<<ld)|z)<<ld)|y)<<ld)|x);
}

__device__ __forceinline__ float chan(const float4&a0,const float4&a1,const float4&a2,const float4&a3,int c){
  const float4& f = (c<4)?a0:((c<8)?a1:((c<12)?a2:a3));
  int r=c&3;
  return r==0?f.x:(r==1?f.y:(r==2?f.z:f.w));
}

// block-hierarchical list append: ballot -> LDS -> ONE global atomic per block.
__device__ __forceinline__ void append_list(bool a, int v, int* __restrict__ list, int* __restrict__ cnt){
  __shared__ int lcnt, lbase;
  __shared__ int woff[TPB/64];
  if(threadIdx.x==0) lcnt=0;
  __syncthreads();
  unsigned long long bl = __ballot(a);
  int lane = threadIdx.x & 63;
  int wv = threadIdx.x >> 6;
  if(lane==0){ int pop=__popcll(bl); woff[wv] = pop ? atomicAdd(&lcnt,pop) : 0; }
  __syncthreads();
  if(threadIdx.x==0 && lcnt) lbase = atomicAdd(cnt, lcnt);
  __syncthreads();
  if(a) list[lbase + woff[wv] + __popcll(bl & ((1ull<<lane)-1ull))] = v;
}

// stats for thread-per-voxel kernels (16 channels per thread)
__device__ __forceinline__ void stats_reduce(const float4&a0,const float4&a1,const float4&a2,const float4&a3,
                                             float* red, float* __restrict__ gsums){
  int lane=threadIdx.x&63, wv=threadIdx.x>>6, nw=blockDim.x>>6;
  #pragma unroll
  for(int c=0;c<16;c++){
    float x = chan(a0,a1,a2,a3,c);
    float q = x*x;
    for(int o=32;o>0;o>>=1){ x+=__shfl_down(x,o,64); q+=__shfl_down(q,o,64); }
    if(lane==0){ red[wv*32+c]=x; red[wv*32+16+c]=q; }
  }
  __syncthreads();
  if(threadIdx.x<32){
    float t=0.f;
    for(int w=0;w<nw;w++) t+=red[w*32+threadIdx.x];
    atomicAdd(&gsums[threadIdx.x], t);
  }
}

// stats for co-split kernels: thread holds channels 4*sub..4*sub+3 (sub = tid&3)
__device__ __forceinline__ void stats_reduce4(const float4&a, float* red, float* __restrict__ gsums){
  int lane=threadIdx.x&63, wv=threadIdx.x>>6, nw=blockDim.x>>6;
  float sx[4]={a.x,a.y,a.z,a.w};
  float sq[4]={a.x*a.x,a.y*a.y,a.z*a.z,a.w*a.w};
  for(int o=32;o>=4;o>>=1){
    #pragma unroll
    for(int k=0;k<4;k++){ sx[k]+=__shfl_down(sx[k],o,64); sq[k]+=__shfl_down(sq[k],o,64); }
  }
  if(lane<4){
    #pragma unroll
    for(int k=0;k<4;k++){ red[wv*32+lane*4+k]=sx[k]; red[wv*32+16+lane*4+k]=sq[k]; }
  }
  __syncthreads();
  if(threadIdx.x<32){
    float t=0.f;
    for(int w=0;w<nw;w++) t+=red[w*32+threadIdx.x];
    atomicAdd(&gsums[threadIdx.x], t);
  }
}

__global__ __launch_bounds__(TPB) void k_scatter(const float* __restrict__ data, const int* __restrict__ cl,
                                                 int n, float* __restrict__ c0){
  int i = blockIdx.x*blockDim.x + threadIdx.x;
  if(i>=n) return;
  int z=(int)data[i*5+0], y=(int)data[i*5+1], x=(int)data[i*5+2];
  atomicAdd(&c0[vox(cl[i],z,y,x,6)], 1.0f);
}

// ---- ordered 3-phase compaction of the L0 occupancy grid ----
__global__ __launch_bounds__(TPB) void k_cnt0(const float* __restrict__ c0, int n, int* __restrict__ bc){
  int i = blockIdx.x*TPB + threadIdx.x;
  bool a = (i<n) && (c0[i]>0.f);
  unsigned long long bl = __ballot(a);
  __shared__ int wcnt[TPB/64];
  int lane=threadIdx.x&63, wv=threadIdx.x>>6;
  if(lane==0) wcnt[wv]=__popcll(bl);
  __syncthreads();
  if(threadIdx.x==0) bc[blockIdx.x]=wcnt[0]+wcnt[1]+wcnt[2]+wcnt[3];
}

__global__ __launch_bounds__(1024) void k_scan0(int* __restrict__ bc, int nb, int* __restrict__ total){
  __shared__ int s[1024];
  int t=threadIdx.x, b4=t*4;
  int v0 = (b4+0<nb)?bc[b4+0]:0;
  int v1 = (b4+1<nb)?bc[b4+1]:0;
  int v2 = (b4+2<nb)?bc[b4+2]:0;
  int v3 = (b4+3<nb)?bc[b4+3]:0;
  int sum=v0+v1+v2+v3;
  s[t]=sum; __syncthreads();
  for(int o=1;o<1024;o<<=1){
    int x = (t>=o)? s[t-o] : 0;
    __syncthreads();
    s[t]+=x;
    __syncthreads();
  }
  int excl=s[t]-sum;
  if(b4+0<nb) bc[b4+0]=excl;
  if(b4+1<nb) bc[b4+1]=excl+v0;
  if(b4+2<nb) bc[b4+2]=excl+v0+v1;
  if(b4+3<nb) bc[b4+3]=excl+v0+v1+v2;
  if(t==1023) *total = s[1023];
}

__global__ __launch_bounds__(TPB) void k_emit0(const float* __restrict__ c0, int n,
                                               const int* __restrict__ bc, int* __restrict__ list){
  int i = blockIdx.x*TPB + threadIdx.x;
  bool a = (i<n) && (c0[i]>0.f);
  unsigned long long bl = __ballot(a);
  __shared__ int woff[TPB/64];
  __shared__ int wpre[TPB/64];
  int lane=threadIdx.x&63, wv=threadIdx.x>>6;
  if(lane==0) woff[wv]=__popcll(bl);
  __syncthreads();
  if(threadIdx.x==0){ int acc=0; for(int w=0;w<TPB/64;w++){ wpre[w]=acc; acc+=woff[w]; } }
  __syncthreads();
  if(a) list[bc[blockIdx.x] + wpre[wv] + __popcll(bl&((1ull<<lane)-1ull))] = i;
}

__global__ __launch_bounds__(TPB) void k_markparent_compact(const int* __restrict__ listF, const int* __restrict__ cntF,
        int ldf, int* __restrict__ g, int* __restrict__ listC, int* __restrict__ cntC){
  int i = blockIdx.x*TPB + threadIdx.x;
  bool first=false; int p=0;
  if(i < *cntF){
    int v=listF[i];
    int dm=(1<<ldf)-1;
    int x=v&dm, y=(v>>ldf)&dm, z=(v>>(2*ldf))&dm, b=v>>(3*ldf);
    p=vox(b,z>>1,y>>1,x>>1,ldf-1);
    first = (atomicExch(&g[p],1)==0);
  }
  append_list(first,p,listC,cntC);
}

__global__ __launch_bounds__(TPB) void k_sparsify_compact(float* __restrict__ X, float* __restrict__ Y,
        const int* __restrict__ listA, const int* __restrict__ cntA,
        int* __restrict__ listB, int* __restrict__ cntB, int* __restrict__ gmask){
  int i = blockIdx.x*TPB + threadIdx.x;
  bool keep=false; int v=0;
  if(i < *cntA){
    v = listA[i];
    keep = X[(size_t)v<<4] > 0.f;
    if(!keep){
      float4 zz = make_float4(0,0,0,0);
      float4* px=(float4*)(X+((size_t)v<<4)); px[0]=zz;px[1]=zz;px[2]=zz;px[3]=zz;
      float4* py=(float4*)(Y+((size_t)v<<4)); py[0]=zz;py[1]=zz;py[2]=zz;py[3]=zz;
      if(gmask) gmask[v]=0;
    }
  }
  append_list(keep,v,listB,cntB);
}

// prepare: 1 -> 16 ch, k=3 SAME; LDS weights; fused stats
__global__ __launch_bounds__(TPB) void k_prep_l(const float* __restrict__ c0, const int* __restrict__ list,
          const int* __restrict__ cnt, const float* __restrict__ w, float* __restrict__ X,
          float* __restrict__ gsums){
  __shared__ float wl[432];
  __shared__ float red[(TPB/64)*32];
  for(int i=threadIdx.x;i<432;i+=TPB) wl[i]=w[i];
  __syncthreads();
  int i = blockIdx.x*TPB + threadIdx.x;
  bool act = i < *cnt;
  float4 a0=make_float4(0,0,0,0), a1=a0, a2=a0, a3=a0;
  if(act){
    int v=list[i];
    int x=v&63, y=(v>>6)&63, z=(v>>12)&63, b=v>>18;
    for(int dz=0;dz<3;dz++){ int zz=z+dz-1; if((unsigned)zz>=64u) continue;
      for(int dy=0;dy<3;dy++){ int yy=y+dy-1; if((unsigned)yy>=64u) continue;
        for(int dx=0;dx<3;dx++){ int xx=x+dx-1; if((unsigned)xx>=64u) continue;
          float av = c0[vox(b,zz,yy,xx,6)];
          if(av==0.f) continue;
          const float4* wv=(const float4*)&wl[((dz*3+dy)*3+dx)<<4];
          fma4(a0,av,wv[0]); fma4(a1,av,wv[1]); fma4(a2,av,wv[2]); fma4(a3,av,wv[3]);
        }
      }
    }
    float4* o=(float4*)(X+((size_t)v<<4));
    o[0]=a0;o[1]=a1;o[2]=a2;o[3]=a3;
  }
  stats_reduce(a0,a1,a2,a3,red,gsums);
}

// 16->16 k=3 SAME conv, co-split, tap-gated by activity grid
__global__ __launch_bounds__(CTPB) void k_conv3_l(const float* __restrict__ Xin, const int* __restrict__ list,
      const int* __restrict__ cnt, const float* __restrict__ w, const int* __restrict__ actg,
      float* __restrict__ Xout, int ld){
  __shared__ float wl[6912];
  int nwork = *cnt;
  if((int)((blockIdx.x*CTPB)>>2) >= nwork) return;
  for(int i=threadIdx.x;i<6912;i+=CTPB) wl[i]=w[i];
  __syncthreads();
  int t = blockIdx.x*CTPB + threadIdx.x;
  int i = t>>2, sub = t&3;
  if(i >= nwork) return;
  int v = list[i];
  int d=1<<ld, dm=d-1;
  int x=v&dm, y=(v>>ld)&dm, z=(v>>(2*ld))&dm, b=v>>(3*ld);
  float4 acc=make_float4(0,0,0,0);
  for(int dz=0;dz<3;dz++){ int zz=z+dz-1; if((unsigned)zz>=(unsigned)d) continue;
    for(int dy=0;dy<3;dy++){ int yy=y+dy-1; if((unsigned)yy>=(unsigned)d) continue;
      int rb = vox(b,zz,yy,0,ld);
      const float* srow = Xin + ((size_t)rb<<4);
      const int* arow = actg + rb;
      int m[3];
      #pragma unroll
      for(int dx=0;dx<3;dx++){ int xx=x+dx-1; m[dx] = ((unsigned)xx<(unsigned)d) ? arow[xx] : 0; }
      const float* wrow = &wl[(((dz*3+dy)*3)<<8) + (sub<<2)];
      #pragma unroll
      for(int dx=0;dx<3;dx++){
        if(!m[dx]) continue;
        int xx=x+dx-1;
        const float4* sp=(const float4*)(srow + ((size_t)xx<<4));
        float s[16];
        *(float4*)&s[0]=sp[0]; *(float4*)&s[4]=sp[1]; *(float4*)&s[8]=sp[2]; *(float4*)&s[12]=sp[3];
        const float* wt = wrow + (dx<<8);
        #pragma unroll
        for(int ci=0;ci<16;ci++)
          fma4(acc, s[ci], *(const float4*)(wt + (ci<<4)));
      }
    }
  }
  ((float4*)(Xout + ((size_t)v<<4)))[sub] = acc;
}

// k=4 pad(1,2) conv, co-split, tap-gated, two-phase 32KB weight staging; fused stats
__global__ __launch_bounds__(CTPB) void k_conv4_l(const float* __restrict__ Xin, const int* __restrict__ list,
      const int* __restrict__ cnt, const float* __restrict__ w, const int* __restrict__ actg,
      float* __restrict__ Xout, int ld, float* __restrict__ gsums){
  __shared__ float wl[8192];
  __shared__ float red[(CTPB/64)*32];
  int nwork = *cnt;
  if((int)((blockIdx.x*CTPB)>>2) >= nwork) return;
  int t = blockIdx.x*CTPB + threadIdx.x;
  int i = t>>2, sub = t&3;
  bool act = i < nwork;
  int v=0,x=0,y=0,z=0,b=0,d=1<<ld,dm=d-1;
  if(act){
    v = list[i];
    x=v&dm; y=(v>>ld)&dm; z=(v>>(2*ld))&dm; b=v>>(3*ld);
  }
  float4 acc=make_float4(0,0,0,0);
  for(int half=0;half<2;half++){
    __syncthreads();
    for(int k=threadIdx.x;k<8192;k+=CTPB) wl[k]=w[half*8192+k];
    __syncthreads();
    if(act){
      for(int dzl=0;dzl<2;dzl++){ int dz=half*2+dzl;
        int zz=z+dz-1; if((unsigned)zz>=(unsigned)d) continue;
        for(int dy=0;dy<4;dy++){ int yy=y+dy-1; if((unsigned)yy>=(unsigned)d) continue;
          int rb = vox(b,zz,yy,0,ld);
          const float* srow = Xin + ((size_t)rb<<4);
          const int* arow = actg + rb;
          int m[4];
          #pragma unroll
          for(int dx=0;dx<4;dx++){ int xx=x+dx-1; m[dx] = ((unsigned)xx<(unsigned)d) ? arow[xx] : 0; }
          const float* wrow = &wl[((dzl*4+dy)<<10) + (sub<<2)];
          #pragma unroll
          for(int dx=0;dx<4;dx++){
            if(!m[dx]) continue;
            int xx=x+dx-1;
            const float4* sp=(const float4*)(srow + ((size_t)xx<<4));
            float s[16];
            *(float4*)&s[0]=sp[0]; *(float4*)&s[4]=sp[1]; *(float4*)&s[8]=sp[2]; *(float4*)&s[12]=sp[3];
            const float* wt = wrow + (dx<<8);
            #pragma unroll
            for(int ci=0;ci<16;ci++)
              fma4(acc, s[ci], *(const float4*)(wt + (ci<<4)));
          }
        }
      }
    }
  }
  if(act) ((float4*)(Xout + ((size_t)v<<4)))[sub] = acc;
  __syncthreads();
  stats_reduce4(acc, red, gsums);
}

// strided k=2 s=2 VALID down-conv, co-split, child-gated by fine activity grid; fused stats
__global__ __launch_bounds__(TPB) void k_down_l(const float* __restrict__ Xin, const int* __restrict__ list,
      const int* __restrict__ cnt, const float* __restrict__ w, const int* __restrict__ actf,
      float* __restrict__ Xout, int ldc, float* __restrict__ gsums){
  __shared__ float wl[2048];
  __shared__ float red[(TPB/64)*32];
  int nwork = *cnt;
  for(int k=threadIdx.x;k<2048;k+=TPB) wl[k]=w[k];
  __syncthreads();
  int t = blockIdx.x*TPB + threadIdx.x;
  int i = t>>2, sub = t&3;
  bool act = i < nwork;
  float4 acc=make_float4(0,0,0,0);
  if(act){
    int v = list[i];
    int dm=(1<<ldc)-1, ldf=ldc+1;
    int x=v&dm, y=(v>>ldc)&dm, z=(v>>(2*ldc))&dm, b=v>>(3*ldc);
    for(int dz=0;dz<2;dz++) for(int dy=0;dy<2;dy++) for(int dx=0;dx<2;dx++){
      int fi = vox(b,2*z+dz,2*y+dy,2*x+dx,ldf);
      if(!actf[fi]) continue;
      const float4* sp=(const float4*)(Xin + ((size_t)fi<<4));
      float s[16];
      *(float4*)&s[0]=sp[0]; *(float4*)&s[4]=sp[1]; *(float4*)&s[8]=sp[2]; *(float4*)&s[12]=sp[3];
      const float* wt=&wl[((((dz<<1)|dy)<<1 | dx)<<8) + (sub<<2)];
      #pragma unroll
      for(int ci=0;ci<16;ci++)
        fma4(acc, s[ci], *(const float4*)(wt+(ci<<4)));
    }
    ((float4*)(Xout+((size_t)v<<4)))[sub] = acc;
  }
  stats_reduce4(acc, red, gsums);
}

// conv_transpose k=2 s=2 with BN+ReLU folded onto the coarse operand; LDS weights
__global__ __launch_bounds__(TPB) void k_upbn_l(const float* __restrict__ Xc, const int* __restrict__ list,
      const int* __restrict__ cnt, const float* __restrict__ w,
      const float* __restrict__ sums, const int* __restrict__ bncnt,
      const float* __restrict__ g, const float* __restrict__ bta,
      const int* __restrict__ gmask, float* __restrict__ Xf, int ldf){
  __shared__ float wl[2048];
  __shared__ float sc[16], sh[16];
  for(int k=threadIdx.x;k<2048;k+=TPB) wl[k]=w[k];
  if(threadIdx.x<16){
    int c=threadIdx.x;
    float n=(float)(*bncnt); if(n<1.f) n=1.f;
    float mean=sums[c]/n;
    float var=sums[16+c]/n - mean*mean;
    float s=g[c]/sqrtf(var+1e-4f);
    sc[c]=s; sh[c]=fmaf(-mean,s,bta[c]);
  }
  __syncthreads();
  int i = blockIdx.x*TPB + threadIdx.x;
  if(i >= *cnt) return;
  int v = list[i];
  int dm=(1<<ldf)-1, ldc=ldf-1;
  int x=v&dm, y=(v>>ldf)&dm, z=(v>>(2*ldf))&dm, b=v>>(3*ldf);
  int p = vox(b,z>>1,y>>1,x>>1,ldc);
  float4 a0=make_float4(0,0,0,0), a1=a0, a2=a0, a3=a0;
  if(gmask[p]!=0){
    const float4* sp=(const float4*)(Xc + ((size_t)p<<4));
    float s[16];
    *(float4*)&s[0]=sp[0]; *(float4*)&s[4]=sp[1]; *(float4*)&s[8]=sp[2]; *(float4*)&s[12]=sp[3];
    #pragma unroll
    for(int ci=0;ci<16;ci++){ float xh=fmaf(s[ci],sc[ci],sh[ci]); s[ci]=xh>0.f?xh:0.f; }
    int tpar = ((((z&1)^1)<<1 | ((y&1)^1))<<1) | ((x&1)^1);
    const float* wt=&wl[tpar<<8];
    #pragma unroll
    for(int ci=0;ci<16;ci++){
      float av=s[ci];
      const float4* wv=(const float4*)(wt+(ci<<4));
      fma4(a0,av,wv[0]); fma4(a1,av,wv[1]); fma4(a2,av,wv[2]); fma4(a3,av,wv[3]);
    }
  }
  float4* o=(float4*)(Xf+((size_t)v<<4));
  o[0]=a0;o[1]=a1;o[2]=a2;o[3]=a3;
}

__global__ __launch_bounds__(TPB) void k_bnapply(float* __restrict__ X, const int* __restrict__ list,
        const int* __restrict__ cnt, const float* __restrict__ sums,
        const float* __restrict__ g, const float* __restrict__ bta){
  __shared__ float sc[16], sh[16];
  if(threadIdx.x<16){
    int c=threadIdx.x;
    float n=(float)(*cnt); if(n<1.f) n=1.f;
    float mean=sums[c]/n;
    float var=sums[16+c]/n - mean*mean;
    float s=g[c]/sqrtf(var+1e-4f);
    sc[c]=s; sh[c]=fmaf(-mean,s,bta[c]);
  }
  __syncthreads();
  int i = blockIdx.x*TPB + threadIdx.x;
  if(i>=*cnt) return;
  float* p = X + ((size_t)list[i]<<4);
  #pragma unroll
  for(int c=0;c<16;c++){
    float xh = fmaf(p[c], sc[c], sh[c]);
    p[c] = xh>0.f ? xh : 0.f;
  }
}

__global__ __launch_bounds__(TPB) void k_hidden(const float* __restrict__ X3, float* __restrict__ out){
  int i = blockIdx.x*TPB + threadIdx.x;
  if(i>=4*8192) return;
  int b=i>>13, r=i&8191, c=r>>9, s=r&511;
  out[i] = X3[(((size_t)((b<<9)|s))<<4)|c];
}

// output conv 16 -> 1, k=3 SAME; LDS weights; tap-gated
__global__ __launch_bounds__(TPB) void k_final_l(const float* __restrict__ Xin, const int* __restrict__ list,
      const int* __restrict__ cnt, const float* __restrict__ w, const int* __restrict__ actg,
      float* __restrict__ out){
  __shared__ float wl[432];
  for(int k=threadIdx.x;k<432;k+=TPB) wl[k]=w[k];
  __syncthreads();
  int i = blockIdx.x*TPB + threadIdx.x;
  if(i >= *cnt) return;
  int v = list[i];
  float acc=0.f;
  int x=v&63, y=(v>>6)&63, z=(v>>12)&63, b=v>>18;
  for(int dz=0;dz<3;dz++){ int zz=z+dz-1; if((unsigned)zz>=64u) continue;
    for(int dy=0;dy<3;dy++){ int yy=y+dy-1; if((unsigned)yy>=64u) continue;
      int rb = vox(b,zz,yy,0,6);
      const int* arow = actg + rb;
      int m[3];
      #pragma unroll
      for(int dx=0;dx<3;dx++){ int xx=x+dx-1; m[dx] = ((unsigned)xx<64u) ? arow[xx] : 0; }
      #pragma unroll
      for(int dx=0;dx<3;dx++){
        if(!m[dx]) continue;
        int xx=x+dx-1;
        const float* sp = Xin + ((size_t)(rb+xx)<<4);
        const float* wt = &wl[((dz*3+dy)*3+dx)<<4];
        #pragma unroll
        for(int ci=0;ci<16;ci++) acc = fmaf(sp[ci], wt[ci], acc);
      }
    }
  }
  out[v]=acc;
}

static inline int nb(int n){ return (n+TPB-1)/TPB; }
static inline int nbC(int n){ return (n+CTPB-1)/CTPB; }
static inline size_t rbytes(int ld){ return ((size_t)4<<(3*ld))*64; }

extern "C" void kernel_launch(void* const* d_in, const int* in_sizes, int n_in,
                              void* d_out, int out_size, void* d_ws, size_t ws_size,
                              hipStream_t stream){
  const float* data   = (const float*)d_in[0];
  const int*   cl     = (const int*)d_in[1];
  const float* w_prep = (const float*)d_in[2];
  const float* enc_g  = (const float*)d_in[3];
  const float* enc_b  = (const float*)d_in[4];
  const float* enc_ws = (const float*)d_in[5];
  const float* enc_wd = (const float*)d_in[6];
  const float* dec_g  = (const float*)d_in[7];
  const float* dec_b  = (const float*)d_in[8];
  const float* dec_wu = (const float*)d_in[9];
  const float* dec_w3 = (const float*)d_in[10];
  const float* dec_w4 = (const float*)d_in[11];
  const float* w_out  = (const float*)d_in[12];
  int N = in_sizes[0]/5;
  float* outp = (float*)d_out;

  const size_t FEAT_ROOMY = 38305792;
  const size_t FEAT_TIGHT = 33554432;
  const size_t TAILN      = 1048576 + 149504 + 224 + 16 + 4096 + 821248;
  bool roomy = ws_size >= (FEAT_ROOMY + TAILN)*sizeof(float);

  float* ws = (float*)d_ws;
  float *A[4]={0,0,0,0}, *B[4]={0,0,0,0}, *X=0, *Y=0;
  size_t featsz;
  if(roomy){
    A[0]=ws;            B[0]=A[0]+16777216;
    A[1]=B[0]+16777216; B[1]=A[1]+2097152;
    A[2]=B[1]+2097152;  B[2]=A[2]+262144;
    A[3]=B[2]+262144;
    featsz=FEAT_ROOMY;
  } else { X=ws; Y=X+16777216; featsz=FEAT_TIGHT; }
  float* c0 = ws + featsz;
  int* g1=(int*)(c0+1048576); int* g2=g1+131072; int* g3=g2+16384;
  float* sums=(float*)(g3+2048);
  int* counts=(int*)(sums+224);
  int* bc=counts+16;
  int* l0a=bc+4096; int* l0b=l0a+262144; int* l1a=l0b+262144; int* l1b=l1a+131072;
  int* l2a=l1b+131072; int* l2b=l2a+16384; int* l3=l2b+16384;
  int* la[4]={l0a,l1a,l2a,l3};
  int* lb[3]={l0b,l1b,l2b};
  int* g[4]={nullptr,g1,g2,g3};
  int* actF[4]={(int*)c0, g1, g2, g3};   // activity grids per level
  int b0 = N<262144?N:262144;
  int bounds[4]={b0,131072,16384,2048};

  if(roomy){
    hipMemsetAsync(A[3], 0, 32768*sizeof(float), stream);  // hidden reads L3 densely
  } else {
    hipMemsetAsync(ws, 0, featsz*sizeof(float), stream);
  }
  hipMemsetAsync(c0, 0, (1048576+149504+224+16+4096)*sizeof(float), stream);

  k_scatter<<<nb(N),TPB,0,stream>>>(data, cl, N, c0);
  k_cnt0 <<<4096,TPB,0,stream>>>(c0, 1048576, bc);
  k_scan0<<<1,1024,0,stream>>>(bc, 4096, counts+0);
  k_emit0<<<4096,TPB,0,stream>>>(c0, 1048576, bc, l0a);

  if(roomy){
    k_prep_l<<<nb(b0),TPB,0,stream>>>(c0, l0a, counts+0, w_prep, A[0], sums);
    for(int i=0;i<3;i++){
      int ld=6-i;
      k_bnapply<<<nb(bounds[i]),TPB,0,stream>>>(A[i], la[i], counts+i, sums+32*i, enc_g+16*i, enc_b+16*i);
      k_conv3_l<<<nbC(4*bounds[i]),CTPB,0,stream>>>(A[i], la[i], counts+i, enc_ws+6912*i, actF[i], B[i], ld);
      k_markparent_compact<<<nb(bounds[i]),TPB,0,stream>>>(la[i], counts+i, ld, g[i+1], la[i+1], counts+(i+1));
      k_down_l<<<nb(4*bounds[i+1]),TPB,0,stream>>>(B[i], la[i+1], counts+(i+1), enc_wd+2048*i, actF[i], A[i+1], ld-1, sums+32*(i+1));
    }
    k_hidden<<<nb(32768),TPB,0,stream>>>(A[3], outp);
    for(int j=0;j<3;j++){
      int lvl=2-j, ldf=6-lvl;
      const int* bncnt = (j==0)? counts+3 : counts+4+(lvl+1);
      k_upbn_l<<<nb(bounds[lvl]),TPB,0,stream>>>(A[lvl+1], la[lvl], counts+lvl, dec_wu+2048*j,
            sums+32*(3+j), bncnt, dec_g+16*j, dec_b+16*j, g[lvl+1], A[lvl], ldf);
      k_conv3_l<<<nbC(4*bounds[lvl]),CTPB,0,stream>>>(A[lvl], la[lvl], counts+lvl, dec_w3+6912*j, actF[lvl], B[lvl], ldf);
      k_sparsify_compact<<<nb(bounds[lvl]),TPB,0,stream>>>(B[lvl], A[lvl], la[lvl], counts+lvl, lb[lvl], counts+4+lvl, g[lvl]);
      float* ss = (j<2)? sums+32*(4+j) : sums+32*6;
      k_conv4_l<<<nbC(4*bounds[lvl]),CTPB,0,stream>>>(B[lvl], lb[lvl], counts+4+lvl, dec_w4+16384*j, actF[lvl], A[lvl], ldf, ss);
    }
    hipMemsetAsync(outp+32768, 0, (size_t)1048576*sizeof(float), stream);
    k_final_l<<<nb(b0),TPB,0,stream>>>(A[0], lb[0], counts+4, w_out, actF[0], outp+32768);
  } else {
    k_prep_l<<<nb(b0),TPB,0,stream>>>(c0, l0a, counts+0, w_prep, X, sums);
    float* cur=X; float* oth=Y; int ld=6;
    for(int i=0;i<3;i++){
      k_bnapply<<<nb(bounds[i]),TPB,0,stream>>>(cur, la[i], counts+i, sums+32*i, enc_g+16*i, enc_b+16*i);
      hipMemsetAsync(oth, 0, rbytes(ld), stream);
      k_conv3_l<<<nbC(4*bounds[i]),CTPB,0,stream>>>(cur, la[i], counts+i, enc_ws+6912*i, actF[i], oth, ld);
      { float* t=cur; cur=oth; oth=t; }
      k_markparent_compact<<<nb(bounds[i]),TPB,0,stream>>>(la[i], counts+i, ld, g[i+1], la[i+1], counts+(i+1));
      hipMemsetAsync(oth, 0, rbytes(ld-1), stream);
      k_down_l<<<nb(4*bounds[i+1]),TPB,0,stream>>>(cur, la[i+1], counts+(i+1), enc_wd+2048*i, actF[i], oth, ld-1, sums+32*(i+1));
      { float* t=cur; cur=oth; oth=t; }
      ld--;
    }
    k_hidden<<<nb(32768),TPB,0,stream>>>(cur, outp);
    for(int j=0;j<3;j++){
      int lvl=2-j, ldf=ld+1;
      const int* bncnt = (j==0)? counts+3 : counts+4+(lvl+1);
      hipMemsetAsync(oth, 0, rbytes(ldf), stream);
      k_upbn_l<<<nb(bounds[lvl]),TPB,0,stream>>>(cur, la[lvl], counts+lvl, dec_wu+2048*j,
            sums+32*(3+j), bncnt, dec_g+16*j, dec_b+16*j, g[lvl+1], oth, ldf);
      { float* t=cur; cur=oth; oth=t; }
      hipMemsetAsync(oth, 0, rbytes(ldf), stream);
      k_conv3_l<<<nbC(4*bounds[lvl]),CTPB,0,stream>>>(cur, la[lvl], counts+lvl, dec_w3+6912*j, actF[lvl], oth, ldf);
      { float* t=cur; cur=oth; oth=t; }
      k_sparsify_compact<<<nb(bounds[lvl]),TPB,0,stream>>>(cur, oth, la[lvl], counts+lvl, lb[lvl], counts+4+lvl, g[lvl]);
      float* ss = (j<2)? sums+32*(4+j) : sums+32*6;
      k_conv4_l<<<nbC(4*bounds[lvl]),CTPB,0,stream>>>(cur, lb[lvl], counts+4+lvl, dec_w4+16384*j, actF[lvl], oth, ldf, ss);
      { float* t=cur; cur=oth; oth=t; }
      ld=ldf;
    }
    hipMemsetAsync(outp+32768, 0, (size_t)1048576*sizeof(float), stream);
    k_final_l<<<nb(b0),TPB,0,stream>>>(cur, lb[0], counts+4, w_out, actF[0], outp+32768);
  }
}

// Round 11
// 638.347 us; speedup vs baseline: 1.6421x; 1.1381x over previous
//
#include <hip/hip_runtime.h>

#define TPB 256
#define CTPB 512

typedef unsigned long long ull;

__device__ __forceinline__ void fma4(float4& a, float s, const float4 b){
  a.x = fmaf(s,b.x,a.x); a.y = fmaf(s,b.y,a.y);
  a.z = fmaf(s,b.z,a.z); a.w = fmaf(s,b.w,a.w);
}

__device__ __forceinline__ int vox(int b,int z,int y,int x,int ld){
  return ((((((b<<ld)|z)<<ld)|y)<<ld)|x);
}

__device__ __forceinline__ float chan(const float4&a0,const float4&a1,const float4&a2,const float4&a3,int c){
  const float4& f = (c<4)?a0:((c<8)?a1:((c<12)?a2:a3));
  int r=c&3;
  return r==0?f.x:(r==1?f.y:(r==2?f.z:f.w));
}

// block-hierarchical list append; returns emit position (valid when a)
__device__ __forceinline__ int append_list(bool a, int v, int* __restrict__ list, int* __restrict__ cnt){
  __shared__ int lcnt, lbase;
  __shared__ int woff[TPB/64];
  if(threadIdx.x==0) lcnt=0;
  __syncthreads();
  unsigned long long bl = __ballot(a);
  int lane = threadIdx.x & 63;
  int wv = threadIdx.x >> 6;
  if(lane==0){ int pop=__popcll(bl); woff[wv] = pop ? atomicAdd(&lcnt,pop) : 0; }
  __syncthreads();
  if(threadIdx.x==0 && lcnt) lbase = atomicAdd(cnt, lcnt);
  __syncthreads();
  int pos = -1;
  if(a){
    pos = lbase + woff[wv] + __popcll(bl & ((1ull<<lane)-1ull));
    list[pos] = v;
  }
  return pos;
}

__device__ __forceinline__ void stats_reduce(const float4&a0,const float4&a1,const float4&a2,const float4&a3,
                                             float* red, float* __restrict__ gsums){
  int lane=threadIdx.x&63, wv=threadIdx.x>>6, nw=blockDim.x>>6;
  #pragma unroll
  for(int c=0;c<16;c++){
    float x = chan(a0,a1,a2,a3,c);
    float q = x*x;
    for(int o=32;o>0;o>>=1){ x+=__shfl_down(x,o,64); q+=__shfl_down(q,o,64); }
    if(lane==0){ red[wv*32+c]=x; red[wv*32+16+c]=q; }
  }
  __syncthreads();
  if(threadIdx.x<32){
    float t=0.f;
    for(int w=0;w<nw;w++) t+=red[w*32+threadIdx.x];
    atomicAdd(&gsums[threadIdx.x], t);
  }
}

__device__ __forceinline__ void stats_reduce4(const float4&a, float* red, float* __restrict__ gsums){
  int lane=threadIdx.x&63, wv=threadIdx.x>>6, nw=blockDim.x>>6;
  float sx[4]={a.x,a.y,a.z,a.w};
  float sq[4]={a.x*a.x,a.y*a.y,a.z*a.z,a.w*a.w};
  for(int o=32;o>=4;o>>=1){
    #pragma unroll
    for(int k=0;k<4;k++){ sx[k]+=__shfl_down(sx[k],o,64); sq[k]+=__shfl_down(sq[k],o,64); }
  }
  if(lane<4){
    #pragma unroll
    for(int k=0;k<4;k++){ red[wv*32+lane*4+k]=sx[k]; red[wv*32+16+lane*4+k]=sq[k]; }
  }
  __syncthreads();
  if(threadIdx.x<32){
    float t=0.f;
    for(int w=0;w<nw;w++) t+=red[w*32+threadIdx.x];
    atomicAdd(&gsums[threadIdx.x], t);
  }
}

__global__ __launch_bounds__(TPB) void k_scatter(const float* __restrict__ data, const int* __restrict__ cl,
                                                 int n, float* __restrict__ c0){
  int i = blockIdx.x*blockDim.x + threadIdx.x;
  if(i>=n) return;
  int z=(int)data[i*5+0], y=(int)data[i*5+1], x=(int)data[i*5+2];
  atomicAdd(&c0[vox(cl[i],z,y,x,6)], 1.0f);
}

__global__ __launch_bounds__(TPB) void k_cnt0(const float* __restrict__ c0, int n, int* __restrict__ bc){
  int i = blockIdx.x*TPB + threadIdx.x;
  bool a = (i<n) && (c0[i]>0.f);
  unsigned long long bl = __ballot(a);
  __shared__ int wcnt[TPB/64];
  int lane=threadIdx.x&63, wv=threadIdx.x>>6;
  if(lane==0) wcnt[wv]=__popcll(bl);
  __syncthreads();
  if(threadIdx.x==0) bc[blockIdx.x]=wcnt[0]+wcnt[1]+wcnt[2]+wcnt[3];
}

__global__ __launch_bounds__(1024) void k_scan0(int* __restrict__ bc, int nb, int* __restrict__ total){
  __shared__ int s[1024];
  int t=threadIdx.x, b4=t*4;
  int v0 = (b4+0<nb)?bc[b4+0]:0;
  int v1 = (b4+1<nb)?bc[b4+1]:0;
  int v2 = (b4+2<nb)?bc[b4+2]:0;
  int v3 = (b4+3<nb)?bc[b4+3]:0;
  int sum=v0+v1+v2+v3;
  s[t]=sum; __syncthreads();
  for(int o=1;o<1024;o<<=1){
    int x = (t>=o)? s[t-o] : 0;
    __syncthreads();
    s[t]+=x;
    __syncthreads();
  }
  int excl=s[t]-sum;
  if(b4+0<nb) bc[b4+0]=excl;
  if(b4+1<nb) bc[b4+1]=excl+v0;
  if(b4+2<nb) bc[b4+2]=excl+v0+v1;
  if(b4+3<nb) bc[b4+3]=excl+v0+v1+v2;
  if(t==1023) *total = s[1023];
}

// emit sorted L0 list + free row-occupancy bitboard from the wave ballot (lane == x)
__global__ __launch_bounds__(TPB) void k_emit0(const float* __restrict__ c0, int n,
                                               const int* __restrict__ bc, int* __restrict__ list,
                                               ull* __restrict__ rowb){
  int i = blockIdx.x*TPB + threadIdx.x;
  bool a = (i<n) && (c0[i]>0.f);
  unsigned long long bl = __ballot(a);
  __shared__ int woff[TPB/64];
  __shared__ int wpre[TPB/64];
  int lane=threadIdx.x&63, wv=threadIdx.x>>6;
  if(lane==0){ woff[wv]=__popcll(bl); rowb[i>>6]=bl; }
  __syncthreads();
  if(threadIdx.x==0){ int acc=0; for(int w=0;w<TPB/64;w++){ wpre[w]=acc; acc+=woff[w]; } }
  __syncthreads();
  if(a) list[bc[blockIdx.x] + wpre[wv] + __popcll(bl&((1ull<<lane)-1ull))] = i;
}

// build row bitboards for small (int) activity grids
__global__ __launch_bounds__(TPB) void k_rowbits(const int* __restrict__ g, int d, int nrows,
                                                 ull* __restrict__ out){
  int r = blockIdx.x*TPB + threadIdx.x;
  if(r>=nrows) return;
  const int* base = g + r*d;
  ull w=0;
  for(int x=0;x<d;x++) if(base[x]) w |= (1ull<<x);
  out[r]=w;
}

// per-voxel tap masks from row bitboards: tm4 = 64b (k=4 window, offsets -1..2),
// tm3 = 27b (k=3 window, offsets -1..1). OOB taps = 0.
__global__ __launch_bounds__(TPB) void k_tapmask(const int* __restrict__ list, const int* __restrict__ cnt,
        const ull* __restrict__ rowb, int ld, int* __restrict__ tm3, ull* __restrict__ tm4){
  int i = blockIdx.x*TPB + threadIdx.x;
  if(i>=*cnt) return;
  int v = list[i];
  int d=1<<ld, dm=d-1;
  int x=v&dm, y=(v>>ld)&dm, z=(v>>(2*ld))&dm, b=v>>(3*ld);
  ull t4=0; int t3=0;
  for(int oz=-1;oz<=2;oz++){
    int zz=z+oz; if((unsigned)zz>=(unsigned)d) continue;
    for(int oy=-1;oy<=2;oy++){
      int yy=y+oy; if((unsigned)yy>=(unsigned)d) continue;
      ull row = rowb[vox(b,zz,yy,0,ld)>>ld];
      ull w = (x>=1) ? (row>>(x-1)) : (row<<1);
      int dz=oz+1, dy=oy+1;
      t4 |= (w & 0xFull) << (((dz<<2)|dy)<<2);
      if(oz<=1 && oy<=1) t3 |= ((int)(w & 7ull)) << ((dz*3+dy)*3);
    }
  }
  tm3[i]=t3; tm4[i]=t4;
}

__global__ __launch_bounds__(TPB) void k_markparent_compact(const int* __restrict__ listF, const int* __restrict__ cntF,
        int ldf, int* __restrict__ g, int* __restrict__ listC, int* __restrict__ cntC){
  int i = blockIdx.x*TPB + threadIdx.x;
  bool first=false; int p=0;
  if(i < *cntF){
    int v=listF[i];
    int dm=(1<<ldf)-1;
    int x=v&dm, y=(v>>ldf)&dm, z=(v>>(2*ldf))&dm, b=v>>(3*ldf);
    p=vox(b,z>>1,y>>1,x>>1,ldf-1);
    first = (atomicExch(&g[p],1)==0);
  }
  append_list(first,p,listC,cntC);
}

// sparsify + compact list AND tap masks (lb-position-indexed copies)
__global__ __launch_bounds__(TPB) void k_sparsify_compact(float* __restrict__ X, float* __restrict__ Y,
        const int* __restrict__ listA, const int* __restrict__ cntA,
        int* __restrict__ listB, int* __restrict__ cntB, int* __restrict__ gmask,
        const int* __restrict__ tm3a, const ull* __restrict__ tm4a,
        int* __restrict__ tm3b, ull* __restrict__ tm4b){
  int i = blockIdx.x*TPB + threadIdx.x;
  bool keep=false; int v=0;
  if(i < *cntA){
    v = listA[i];
    keep = X[(size_t)v<<4] > 0.f;
    if(!keep){
      float4 zz = make_float4(0,0,0,0);
      float4* px=(float4*)(X+((size_t)v<<4)); px[0]=zz;px[1]=zz;px[2]=zz;px[3]=zz;
      float4* py=(float4*)(Y+((size_t)v<<4)); py[0]=zz;py[1]=zz;py[2]=zz;py[3]=zz;
      if(gmask) gmask[v]=0;
    }
  }
  int pos = append_list(keep,v,listB,cntB);
  if(keep){ tm3b[pos]=tm3a[i]; tm4b[pos]=tm4a[i]; }
}

// prepare: 1 -> 16 ch, k=3 SAME; LDS weights; fused stats
__global__ __launch_bounds__(TPB) void k_prep_l(const float* __restrict__ c0, const int* __restrict__ list,
          const int* __restrict__ cnt, const float* __restrict__ w, float* __restrict__ X,
          float* __restrict__ gsums){
  __shared__ float wl[432];
  __shared__ float red[(TPB/64)*32];
  for(int i=threadIdx.x;i<432;i+=TPB) wl[i]=w[i];
  __syncthreads();
  int i = blockIdx.x*TPB + threadIdx.x;
  bool act = i < *cnt;
  float4 a0=make_float4(0,0,0,0), a1=a0, a2=a0, a3=a0;
  if(act){
    int v=list[i];
    int x=v&63, y=(v>>6)&63, z=(v>>12)&63, b=v>>18;
    for(int dz=0;dz<3;dz++){ int zz=z+dz-1; if((unsigned)zz>=64u) continue;
      for(int dy=0;dy<3;dy++){ int yy=y+dy-1; if((unsigned)yy>=64u) continue;
        for(int dx=0;dx<3;dx++){ int xx=x+dx-1; if((unsigned)xx>=64u) continue;
          float av = c0[vox(b,zz,yy,xx,6)];
          if(av==0.f) continue;
          const float4* wv=(const float4*)&wl[((dz*3+dy)*3+dx)<<4];
          fma4(a0,av,wv[0]); fma4(a1,av,wv[1]); fma4(a2,av,wv[2]); fma4(a3,av,wv[3]);
        }
      }
    }
    float4* o=(float4*)(X+((size_t)v<<4));
    o[0]=a0;o[1]=a1;o[2]=a2;o[3]=a3;
  }
  stats_reduce(a0,a1,a2,a3,red,gsums);
}

// 16->16 k=3 SAME conv, co-split, bitmask-gated (no bounds checks needed)
__global__ __launch_bounds__(CTPB) void k_conv3_l(const float* __restrict__ Xin, const int* __restrict__ list,
      const int* __restrict__ cnt, const float* __restrict__ w, const int* __restrict__ tm3,
      float* __restrict__ Xout, int ld){
  __shared__ float wl[6912];
  int nwork = *cnt;
  if((int)((blockIdx.x*CTPB)>>2) >= nwork) return;
  for(int i=threadIdx.x;i<6912;i+=CTPB) wl[i]=w[i];
  __syncthreads();
  int t = blockIdx.x*CTPB + threadIdx.x;
  int i = t>>2, sub = t&3;
  if(i >= nwork) return;
  int v = list[i];
  int tmv = tm3[i];
  int dm=(1<<ld)-1;
  int x=v&dm, y=(v>>ld)&dm, z=(v>>(2*ld))&dm, b=v>>(3*ld);
  float4 acc=make_float4(0,0,0,0);
  for(int dz=0;dz<3;dz++){
    int rz=(tmv>>(9*dz))&511; if(!rz) continue;
    int zz=z+dz-1;
    for(int dy=0;dy<3;dy++){
      int rm=(rz>>(3*dy))&7; if(!rm) continue;
      int yy=y+dy-1;
      const float* srow = Xin + ((size_t)vox(b,zz,yy,0,ld)<<4);
      const float* wrow = &wl[(((dz*3+dy)*3)<<8) + (sub<<2)];
      #pragma unroll
      for(int dx=0;dx<3;dx++){
        if(!(rm&(1<<dx))) continue;
        const float4* sp=(const float4*)(srow + ((size_t)(x+dx-1)<<4));
        float s[16];
        *(float4*)&s[0]=sp[0]; *(float4*)&s[4]=sp[1]; *(float4*)&s[8]=sp[2]; *(float4*)&s[12]=sp[3];
        const float* wt = wrow + (dx<<8);
        #pragma unroll
        for(int ci=0;ci<16;ci++)
          fma4(acc, s[ci], *(const float4*)(wt + (ci<<4)));
      }
    }
  }
  ((float4*)(Xout + ((size_t)v<<4)))[sub] = acc;
}

// k=4 pad(1,2) conv, co-split, bitmask-gated, two-phase weight staging; fused stats
__global__ __launch_bounds__(CTPB) void k_conv4_l(const float* __restrict__ Xin, const int* __restrict__ list,
      const int* __restrict__ cnt, const float* __restrict__ w, const ull* __restrict__ tm4,
      float* __restrict__ Xout, int ld, float* __restrict__ gsums){
  __shared__ float wl[8192];
  __shared__ float red[(CTPB/64)*32];
  int nwork = *cnt;
  if((int)((blockIdx.x*CTPB)>>2) >= nwork) return;
  int t = blockIdx.x*CTPB + threadIdx.x;
  int i = t>>2, sub = t&3;
  bool act = i < nwork;
  int v=0,x=0,y=0,z=0,b=0,dm=(1<<ld)-1;
  ull tmv=0;
  if(act){
    v = list[i];
    tmv = tm4[i];
    x=v&dm; y=(v>>ld)&dm; z=(v>>(2*ld))&dm; b=v>>(3*ld);
  }
  float4 acc=make_float4(0,0,0,0);
  for(int half=0;half<2;half++){
    __syncthreads();
    for(int k=threadIdx.x;k<8192;k+=CTPB) wl[k]=w[half*8192+k];
    __syncthreads();
    if(act){
      unsigned hw = (unsigned)(tmv >> (half*32));
      for(int dzl=0;dzl<2;dzl++){
        unsigned r16 = (hw>>(dzl*16)) & 0xFFFFu;
        if(!r16) continue;
        int zz = z + half*2 + dzl - 1;
        for(int dy=0;dy<4;dy++){
          unsigned m4 = (r16>>(dy*4)) & 0xFu;
          if(!m4) continue;
          int yy=y+dy-1;
          const float* srow = Xin + ((size_t)vox(b,zz,yy,0,ld)<<4);
          const float* wrow = &wl[((dzl*4+dy)<<10) + (sub<<2)];
          #pragma unroll
          for(int dx=0;dx<4;dx++){
            if(!(m4&(1u<<dx))) continue;
            const float4* sp=(const float4*)(srow + ((size_t)(x+dx-1)<<4));
            float s[16];
            *(float4*)&s[0]=sp[0]; *(float4*)&s[4]=sp[1]; *(float4*)&s[8]=sp[2]; *(float4*)&s[12]=sp[3];
            const float* wt = wrow + (dx<<8);
            #pragma unroll
            for(int ci=0;ci<16;ci++)
              fma4(acc, s[ci], *(const float4*)(wt + (ci<<4)));
          }
        }
      }
    }
  }
  if(act) ((float4*)(Xout + ((size_t)v<<4)))[sub] = acc;
  __syncthreads();
  stats_reduce4(acc, red, gsums);
}

// strided k=2 s=2 VALID down-conv, co-split, child-gated by fine activity grid; fused stats
__global__ __launch_bounds__(TPB) void k_down_l(const float* __restrict__ Xin, const int* __restrict__ list,
      const int* __restrict__ cnt, const float* __restrict__ w, const int* __restrict__ actf,
      float* __restrict__ Xout, int ldc, float* __restrict__ gsums){
  __shared__ float wl[2048];
  __shared__ float red[(TPB/64)*32];
  int nwork = *cnt;
  for(int k=threadIdx.x;k<2048;k+=TPB) wl[k]=w[k];
  __syncthreads();
  int t = blockIdx.x*TPB + threadIdx.x;
  int i = t>>2, sub = t&3;
  bool act = i < nwork;
  float4 acc=make_float4(0,0,0,0);
  if(act){
    int v = list[i];
    int dm=(1<<ldc)-1, ldf=ldc+1;
    int x=v&dm, y=(v>>ldc)&dm, z=(v>>(2*ldc))&dm, b=v>>(3*ldc);
    for(int dz=0;dz<2;dz++) for(int dy=0;dy<2;dy++) for(int dx=0;dx<2;dx++){
      int fi = vox(b,2*z+dz,2*y+dy,2*x+dx,ldf);
      if(!actf[fi]) continue;
      const float4* sp=(const float4*)(Xin + ((size_t)fi<<4));
      float s[16];
      *(float4*)&s[0]=sp[0]; *(float4*)&s[4]=sp[1]; *(float4*)&s[8]=sp[2]; *(float4*)&s[12]=sp[3];
      const float* wt=&wl[((((dz<<1)|dy)<<1 | dx)<<8) + (sub<<2)];
      #pragma unroll
      for(int ci=0;ci<16;ci++)
        fma4(acc, s[ci], *(const float4*)(wt+(ci<<4)));
    }
    ((float4*)(Xout+((size_t)v<<4)))[sub] = acc;
  }
  stats_reduce4(acc, red, gsums);
}

// conv_transpose k=2 s=2 with BN+ReLU folded onto the coarse operand; LDS weights
__global__ __launch_bounds__(TPB) void k_upbn_l(const float* __restrict__ Xc, const int* __restrict__ list,
      const int* __restrict__ cnt, const float* __restrict__ w,
      const float* __restrict__ sums, const int* __restrict__ bncnt,
      const float* __restrict__ g, const float* __restrict__ bta,
      const int* __restrict__ gmask, float* __restrict__ Xf, int ldf){
  __shared__ float wl[2048];
  __shared__ float sc[16], sh[16];
  for(int k=threadIdx.x;k<2048;k+=TPB) wl[k]=w[k];
  if(threadIdx.x<16){
    int c=threadIdx.x;
    float n=(float)(*bncnt); if(n<1.f) n=1.f;
    float mean=sums[c]/n;
    float var=sums[16+c]/n - mean*mean;
    float s=g[c]/sqrtf(var+1e-4f);
    sc[c]=s; sh[c]=fmaf(-mean,s,bta[c]);
  }
  __syncthreads();
  int i = blockIdx.x*TPB + threadIdx.x;
  if(i >= *cnt) return;
  int v = list[i];
  int dm=(1<<ldf)-1, ldc=ldf-1;
  int x=v&dm, y=(v>>ldf)&dm, z=(v>>(2*ldf))&dm, b=v>>(3*ldf);
  int p = vox(b,z>>1,y>>1,x>>1,ldc);
  float4 a0=make_float4(0,0,0,0), a1=a0, a2=a0, a3=a0;
  if(gmask[p]!=0){
    const float4* sp=(const float4*)(Xc + ((size_t)p<<4));
    float s[16];
    *(float4*)&s[0]=sp[0]; *(float4*)&s[4]=sp[1]; *(float4*)&s[8]=sp[2]; *(float4*)&s[12]=sp[3];
    #pragma unroll
    for(int ci=0;ci<16;ci++){ float xh=fmaf(s[ci],sc[ci],sh[ci]); s[ci]=xh>0.f?xh:0.f; }
    int tpar = ((((z&1)^1)<<1 | ((y&1)^1))<<1) | ((x&1)^1);
    const float* wt=&wl[tpar<<8];
    #pragma unroll
    for(int ci=0;ci<16;ci++){
      float av=s[ci];
      const float4* wv=(const float4*)(wt+(ci<<4));
      fma4(a0,av,wv[0]); fma4(a1,av,wv[1]); fma4(a2,av,wv[2]); fma4(a3,av,wv[3]);
    }
  }
  float4* o=(float4*)(Xf+((size_t)v<<4));
  o[0]=a0;o[1]=a1;o[2]=a2;o[3]=a3;
}

__global__ __launch_bounds__(TPB) void k_bnapply(float* __restrict__ X, const int* __restrict__ list,
        const int* __restrict__ cnt, const float* __restrict__ sums,
        const float* __restrict__ g, const float* __restrict__ bta){
  __shared__ float sc[16], sh[16];
  if(threadIdx.x<16){
    int c=threadIdx.x;
    float n=(float)(*cnt); if(n<1.f) n=1.f;
    float mean=sums[c]/n;
    float var=sums[16+c]/n - mean*mean;
    float s=g[c]/sqrtf(var+1e-4f);
    sc[c]=s; sh[c]=fmaf(-mean,s,bta[c]);
  }
  __syncthreads();
  int i = blockIdx.x*TPB + threadIdx.x;
  if(i>=*cnt) return;
  float* p = X + ((size_t)list[i]<<4);
  #pragma unroll
  for(int c=0;c<16;c++){
    float xh = fmaf(p[c], sc[c], sh[c]);
    p[c] = xh>0.f ? xh : 0.f;
  }
}

__global__ __launch_bounds__(TPB) void k_hidden(const float* __restrict__ X3, float* __restrict__ out){
  int i = blockIdx.x*TPB + threadIdx.x;
  if(i>=4*8192) return;
  int b=i>>13, r=i&8191, c=r>>9, s=r&511;
  out[i] = X3[(((size_t)((b<<9)|s))<<4)|c];
}

// output conv 16 -> 1, k=3 SAME; LDS weights; bitmask-gated
__global__ __launch_bounds__(TPB) void k_final_l(const float* __restrict__ Xin, const int* __restrict__ list,
      const int* __restrict__ cnt, const float* __restrict__ w, const int* __restrict__ tm3,
      float* __restrict__ out){
  __shared__ float wl[432];
  for(int k=threadIdx.x;k<432;k+=TPB) wl[k]=w[k];
  __syncthreads();
  int i = blockIdx.x*TPB + threadIdx.x;
  if(i >= *cnt) return;
  int v = list[i];
  int tmv = tm3[i];
  float acc=0.f;
  int x=v&63, y=(v>>6)&63, z=(v>>12)&63, b=v>>18;
  for(int dz=0;dz<3;dz++){
    int rz=(tmv>>(9*dz))&511; if(!rz) continue;
    int zz=z+dz-1;
    for(int dy=0;dy<3;dy++){
      int rm=(rz>>(3*dy))&7; if(!rm) continue;
      int yy=y+dy-1;
      int rb = vox(b,zz,yy,0,6);
      #pragma unroll
      for(int dx=0;dx<3;dx++){
        if(!(rm&(1<<dx))) continue;
        const float* sp = Xin + ((size_t)(rb+x+dx-1)<<4);
        const float* wt = &wl[((dz*3+dy)*3+dx)<<4];
        #pragma unroll
        for(int ci=0;ci<16;ci++) acc = fmaf(sp[ci], wt[ci], acc);
      }
    }
  }
  out[v]=acc;
}

static inline int nb(int n){ return (n+TPB-1)/TPB; }
static inline int nbC(int n){ return (n+CTPB-1)/CTPB; }
static inline size_t rbytes(int ld){ return ((size_t)4<<(3*ld))*64; }

extern "C" void kernel_launch(void* const* d_in, const int* in_sizes, int n_in,
                              void* d_out, int out_size, void* d_ws, size_t ws_size,
                              hipStream_t stream){
  const float* data   = (const float*)d_in[0];
  const int*   cl     = (const int*)d_in[1];
  const float* w_prep = (const float*)d_in[2];
  const float* enc_g  = (const float*)d_in[3];
  const float* enc_b  = (const float*)d_in[4];
  const float* enc_ws = (const float*)d_in[5];
  const float* enc_wd = (const float*)d_in[6];
  const float* dec_g  = (const float*)d_in[7];
  const float* dec_b  = (const float*)d_in[8];
  const float* dec_wu = (const float*)d_in[9];
  const float* dec_w3 = (const float*)d_in[10];
  const float* dec_w4 = (const float*)d_in[11];
  const float* w_out  = (const float*)d_in[12];
  int N = in_sizes[0]/5;
  float* outp = (float*)d_out;

  const size_t FEAT_ROOMY = 38305792;
  const size_t FEAT_TIGHT = 33554432;
  const size_t TAILN      = 1048576 + 149504 + 224 + 16 + 4096 + 821248 + 2500608;
  bool roomy = ws_size >= (FEAT_ROOMY + TAILN)*sizeof(float);

  float* ws = (float*)d_ws;
  float *A[4]={0,0,0,0}, *B[4]={0,0,0,0}, *X=0, *Y=0;
  size_t featsz;
  if(roomy){
    A[0]=ws;            B[0]=A[0]+16777216;
    A[1]=B[0]+16777216; B[1]=A[1]+2097152;
    A[2]=B[1]+2097152;  B[2]=A[2]+262144;
    A[3]=B[2]+262144;
    featsz=FEAT_ROOMY;
  } else { X=ws; Y=X+16777216; featsz=FEAT_TIGHT; }
  float* c0 = ws + featsz;
  int* g1=(int*)(c0+1048576); int* g2=g1+131072; int* g3=g2+16384;
  float* sums=(float*)(g3+2048);
  int* counts=(int*)(sums+224);
  int* bc=counts+16;
  int* l0a=bc+4096; int* l0b=l0a+262144; int* l1a=l0b+262144; int* l1b=l1a+131072;
  int* l2a=l1b+131072; int* l2b=l2a+16384; int* l3=l2b+16384;
  int* tail = l3+2048;
  ull* rb0=(ull*)tail;            // 16384
  ull* rb1=rb0+16384;             // 4096
  ull* rb2=rb1+4096;              // 1024
  ull* tm4_0=rb2+1024;            // 262144
  ull* tm4_1=tm4_0+262144;        // 131072
  ull* tm4_2=tm4_1+131072;        // 16384
  ull* tm4b_0=tm4_2+16384;
  ull* tm4b_1=tm4b_0+262144;
  ull* tm4b_2=tm4b_1+131072;
  int* tm3_0=(int*)(tm4b_2+16384);
  int* tm3_1=tm3_0+262144;
  int* tm3_2=tm3_1+131072;
  int* tm3b_0=tm3_2+16384;
  int* tm3b_1=tm3b_0+262144;
  int* tm3b_2=tm3b_1+131072;

  int* la[4]={l0a,l1a,l2a,l3};
  int* lb[3]={l0b,l1b,l2b};
  int* g[4]={nullptr,g1,g2,g3};
  int* actF[4]={(int*)c0, g1, g2, g3};
  ull* rbL[3]={rb0,rb1,rb2};
  ull* tm4L[3]={tm4_0,tm4_1,tm4_2};
  ull* tm4bL[3]={tm4b_0,tm4b_1,tm4b_2};
  int* tm3L[3]={tm3_0,tm3_1,tm3_2};
  int* tm3bL[3]={tm3b_0,tm3b_1,tm3b_2};
  int b0 = N<262144?N:262144;
  int bounds[4]={b0,131072,16384,2048};

  if(roomy){
    hipMemsetAsync(A[3], 0, 32768*sizeof(float), stream);  // hidden reads L3 densely
  } else {
    hipMemsetAsync(ws, 0, featsz*sizeof(float), stream);
  }
  hipMemsetAsync(c0, 0, (1048576+149504+224+16+4096)*sizeof(float), stream);

  k_scatter<<<nb(N),TPB,0,stream>>>(data, cl, N, c0);
  k_cnt0 <<<4096,TPB,0,stream>>>(c0, 1048576, bc);
  k_scan0<<<1,1024,0,stream>>>(bc, 4096, counts+0);
  k_emit0<<<4096,TPB,0,stream>>>(c0, 1048576, bc, l0a, rb0);
  k_tapmask<<<nb(b0),TPB,0,stream>>>(l0a, counts+0, rb0, 6, tm3L[0], tm4L[0]);

  if(roomy){
    k_prep_l<<<nb(b0),TPB,0,stream>>>(c0, l0a, counts+0, w_prep, A[0], sums);
    for(int i=0;i<3;i++){
      int ld=6-i;
      k_bnapply<<<nb(bounds[i]),TPB,0,stream>>>(A[i], la[i], counts+i, sums+32*i, enc_g+16*i, enc_b+16*i);
      k_conv3_l<<<nbC(4*bounds[i]),CTPB,0,stream>>>(A[i], la[i], counts+i, enc_ws+6912*i, tm3L[i], B[i], ld);
      k_markparent_compact<<<nb(bounds[i]),TPB,0,stream>>>(la[i], counts+i, ld, g[i+1], la[i+1], counts+(i+1));
      if(i<2){
        int dc=1<<(5-i), nrows=4*dc*dc;
        k_rowbits<<<nb(nrows),TPB,0,stream>>>(g[i+1], dc, nrows, rbL[i+1]);
        k_tapmask<<<nb(bounds[i+1]),TPB,0,stream>>>(la[i+1], counts+(i+1), rbL[i+1], 5-i, tm3L[i+1], tm4L[i+1]);
      }
      k_down_l<<<nb(4*bounds[i+1]),TPB,0,stream>>>(B[i], la[i+1], counts+(i+1), enc_wd+2048*i, actF[i], A[i+1], ld-1, sums+32*(i+1));
    }
    k_hidden<<<nb(32768),TPB,0,stream>>>(A[3], outp);
    for(int j=0;j<3;j++){
      int lvl=2-j, ldf=6-lvl;
      const int* bncnt = (j==0)? counts+3 : counts+4+(lvl+1);
      k_upbn_l<<<nb(bounds[lvl]),TPB,0,stream>>>(A[lvl+1], la[lvl], counts+lvl, dec_wu+2048*j,
            sums+32*(3+j), bncnt, dec_g+16*j, dec_b+16*j, g[lvl+1], A[lvl], ldf);
      k_conv3_l<<<nbC(4*bounds[lvl]),CTPB,0,stream>>>(A[lvl], la[lvl], counts+lvl, dec_w3+6912*j, tm3L[lvl], B[lvl], ldf);
      k_sparsify_compact<<<nb(bounds[lvl]),TPB,0,stream>>>(B[lvl], A[lvl], la[lvl], counts+lvl, lb[lvl], counts+4+lvl, g[lvl],
            tm3L[lvl], tm4L[lvl], tm3bL[lvl], tm4bL[lvl]);
      float* ss = (j<2)? sums+32*(4+j) : sums+32*6;
      k_conv4_l<<<nbC(4*bounds[lvl]),CTPB,0,stream>>>(B[lvl], lb[lvl], counts+4+lvl, dec_w4+16384*j, tm4bL[lvl], A[lvl], ldf, ss);
    }
    hipMemsetAsync(outp+32768, 0, (size_t)1048576*sizeof(float), stream);
    k_final_l<<<nb(b0),TPB,0,stream>>>(A[0], lb[0], counts+4, w_out, tm3bL[0], outp+32768);
  } else {
    k_prep_l<<<nb(b0),TPB,0,stream>>>(c0, l0a, counts+0, w_prep, X, sums);
    float* cur=X; float* oth=Y; int ld=6;
    for(int i=0;i<3;i++){
      k_bnapply<<<nb(bounds[i]),TPB,0,stream>>>(cur, la[i], counts+i, sums+32*i, enc_g+16*i, enc_b+16*i);
      hipMemsetAsync(oth, 0, rbytes(ld), stream);
      k_conv3_l<<<nbC(4*bounds[i]),CTPB,0,stream>>>(cur, la[i], counts+i, enc_ws+6912*i, tm3L[i], oth, ld);
      { float* t=cur; cur=oth; oth=t; }
      k_markparent_compact<<<nb(bounds[i]),TPB,0,stream>>>(la[i], counts+i, ld, g[i+1], la[i+1], counts+(i+1));
      if(i<2){
        int dc=1<<(5-i), nrows=4*dc*dc;
        k_rowbits<<<nb(nrows),TPB,0,stream>>>(g[i+1], dc, nrows, rbL[i+1]);
        k_tapmask<<<nb(bounds[i+1]),TPB,0,stream>>>(la[i+1], counts+(i+1), rbL[i+1], 5-i, tm3L[i+1], tm4L[i+1]);
      }
      hipMemsetAsync(oth, 0, rbytes(ld-1), stream);
      k_down_l<<<nb(4*bounds[i+1]),TPB,0,stream>>>(cur, la[i+1], counts+(i+1), enc_wd+2048*i, actF[i], oth, ld-1, sums+32*(i+1));
      { float* t=cur; cur=oth; oth=t; }
      ld--;
    }
    k_hidden<<<nb(32768),TPB,0,stream>>>(cur, outp);
    for(int j=0;j<3;j++){
      int lvl=2-j, ldf=ld+1;
      const int* bncnt = (j==0)? counts+3 : counts+4+(lvl+1);
      hipMemsetAsync(oth, 0, rbytes(ldf), stream);
      k_upbn_l<<<nb(bounds[lvl]),TPB,0,stream>>>(cur, la[lvl], counts+lvl, dec_wu+2048*j,
            sums+32*(3+j), bncnt, dec_g+16*j, dec_b+16*j, g[lvl+1], oth, ldf);
      { float* t=cur; cur=oth; oth=t; }
      hipMemsetAsync(oth, 0, rbytes(ldf), stream);
      k_conv3_l<<<nbC(4*bounds[lvl]),CTPB,0,stream>>>(cur, la[lvl], counts+lvl, dec_w3+6912*j, tm3L[lvl], oth, ldf);
      { float* t=cur; cur=oth; oth=t; }
      k_sparsify_compact<<<nb(bounds[lvl]),TPB,0,stream>>>(cur, oth, la[lvl], counts+lvl, lb[lvl], counts+4+lvl, g[lvl],
            tm3L[lvl], tm4L[lvl], tm3bL[lvl], tm4bL[lvl]);
      float* ss = (j<2)? sums+32*(4+j) : sums+32*6;
      k_conv4_l<<<nbC(4*bounds[lvl]),CTPB,0,stream>>>(cur, lb[lvl], counts+4+lvl, dec_w4+16384*j, tm4bL[lvl], oth, ldf, ss);
      { float* t=cur; cur=oth; oth=t; }
      ld=ldf;
    }
    hipMemsetAsync(outp+32768, 0, (size_t)1048576*sizeof(float), stream);
    k_final_l<<<nb(b0),TPB,0,stream>>>(cur, lb[0], counts+4, w_out, tm3bL[0], outp+32768);
  }
}